// Round 4
// baseline (313.213 us; speedup 1.0000x reference)
//
#include <hip/hip_runtime.h>

#define BB   4
#define NN   16384
#define KK   32
#define HID  128
#define OUTF 64

typedef _Float16 f16x8 __attribute__((ext_vector_type(8)));
typedef _Float16 f16x4 __attribute__((ext_vector_type(4)));
typedef _Float16 f16x2 __attribute__((ext_vector_type(2)));
typedef float    f32x4 __attribute__((ext_vector_type(4)));

static __device__ __forceinline__ unsigned short h2u(_Float16 h) {
    union { _Float16 h; unsigned short u; } c; c.h = h; return c.u;
}
static __device__ __forceinline__ _Float16 u2h(unsigned short u) {
    union { _Float16 h; unsigned short u; } c; c.u = u; return c.h;
}

// pe column-pair MAC: v = bias2 + t.xy*rx + t.zw*ry + t[4:5]*rz  (v_pk_fma_f16)
#define PE_HALF(T, RX, RY, RZ)                                              \
    (__builtin_shufflevector((T), (T), 6, 7)                                \
     + __builtin_shufflevector((T), (T), 0, 1) * (RX)                       \
     + __builtin_shufflevector((T), (T), 2, 3) * (RY)                       \
     + __builtin_shufflevector((T), (T), 4, 5) * (RZ))

// Array-free pe fragment builder: named temporaries only, relu via pk_max,
// f16x8 assembly via shufflevector (register placement, no insert chains).
#define PE_FRAGS(E, O1, O2)                                                 \
    do {                                                                    \
        _Float16 _hx = u2h((E).x), _hy = u2h((E).y), _hz = u2h((E).z);      \
        f16x2 _rx = { _hx, _hx }, _ry = { _hy, _hy }, _rz = { _hz, _hz };   \
        f16x2 _z = { (_Float16)0.f, (_Float16)0.f };                        \
        f16x2 _a0 = __builtin_elementwise_max(PE_HALF(tab1[0], _rx, _ry, _rz), _z); \
        f16x2 _a1 = __builtin_elementwise_max(PE_HALF(tab1[1], _rx, _ry, _rz), _z); \
        f16x2 _a2 = __builtin_elementwise_max(PE_HALF(tab1[2], _rx, _ry, _rz), _z); \
        f16x2 _a3 = __builtin_elementwise_max(PE_HALF(tab1[3], _rx, _ry, _rz), _z); \
        f16x2 _b0 = __builtin_elementwise_max(PE_HALF(tab2[0], _rx, _ry, _rz), _z); \
        f16x2 _b1 = __builtin_elementwise_max(PE_HALF(tab2[1], _rx, _ry, _rz), _z); \
        f16x2 _b2 = __builtin_elementwise_max(PE_HALF(tab2[2], _rx, _ry, _rz), _z); \
        f16x2 _b3 = __builtin_elementwise_max(PE_HALF(tab2[3], _rx, _ry, _rz), _z); \
        f16x4 _al = __builtin_shufflevector(_a0, _a1, 0, 1, 2, 3);          \
        f16x4 _ah = __builtin_shufflevector(_a2, _a3, 0, 1, 2, 3);          \
        f16x4 _bl = __builtin_shufflevector(_b0, _b1, 0, 1, 2, 3);          \
        f16x4 _bh = __builtin_shufflevector(_b2, _b3, 0, 1, 2, 3);          \
        O1 = __builtin_shufflevector(_al, _ah, 0, 1, 2, 3, 4, 5, 6, 7);     \
        O2 = __builtin_shufflevector(_bl, _bh, 0, 1, 2, 3, 4, 5, 6, 7);     \
    } while (0)

// ---------------------------------------------------------------------------
// prep_all: ONE kernel, no inter-block deps. (verified R6/R7, unchanged)
// ---------------------------------------------------------------------------
__global__ __launch_bounds__(256) void prep_all(
    const float* __restrict__ pe_w2, const float* __restrict__ pe_b2,
    const float* __restrict__ mlp_w1, const float* __restrict__ mlp_b1,
    const float* __restrict__ mlp_w2,
    const float* __restrict__ features, const float* __restrict__ points,
    _Float16* __restrict__ gB1, _Float16* __restrict__ gW2,
    float* __restrict__ b1c,
    _Float16* __restrict__ feat16, float4* __restrict__ pts4)
{
    const int bid = blockIdx.x, tid = threadIdx.x;
    if (bid >= 40) {
        if (bid == 2344) {
            if (tid < HID) {
                float a = mlp_b1[tid];
#pragma unroll 16
                for (int c = 0; c < 64; ++c)
                    a = fmaf(pe_b2[c], mlp_w1[(32 + c) * HID + tid], a);
                b1c[tid] = a;
            }
            return;
        }
        int t = (bid - 40) * 256 + tid;
        if (t < BB * NN * 8) {
            float4 v = ((const float4*)features)[t];
            f16x4 h;
            h[0] = (_Float16)v.x; h[1] = (_Float16)v.y;
            h[2] = (_Float16)v.z; h[3] = (_Float16)v.w;
            *(f16x4*)(feat16 + (size_t)t * 4) = h;
        } else {
            int i = t - BB * NN * 8;
            if (i < BB * NN) {
                const float* p = points + (size_t)i * 3;
                pts4[i] = make_float4(p[0], p[1], p[2], 0.f);
            }
        }
        return;
    }
    if (bid < 24) {   // gB1: tile (ks,nt); element e: l=e>>3, j=e&7
        int ks = bid >> 3, nt = bid & 7;
        for (int e = tid; e < 512; e += 256) {
            int l = e >> 3, j = e & 7;
            int k = ks * 32 + (l >> 4) * 8 + j;
            int n = nt * 16 + (l & 15);
            float v;
            if (k < 32) {
                v = mlp_w1[k * HID + n];
            } else {
                int r = k - 32;
                v = 0.f;
#pragma unroll 16
                for (int c = 0; c < 64; ++c)
                    v = fmaf(pe_w2[r * 64 + c], mlp_w1[(32 + c) * HID + n], v);
            }
            gB1[bid * 512 + e] = (_Float16)v;
        }
    } else {          // gW2 — pre-scaled by 1/32 so hm stores skip the mean mul
        int tb = bid - 24;
        int ks = tb >> 2, nt = tb & 3;
        for (int e = tid; e < 512; e += 256) {
            int l = e >> 3, j = e & 7;
            int k = ks * 32 + (l >> 4) * 8 + j;
            int n = nt * 16 + (l & 15);
            gW2[tb * 512 + e] = (_Float16)(mlp_w2[k * OUTF + n] * 0.03125f);
        }
    }
}

// ---------------------------------------------------------------------------
// Main: R1-champion structure EXACTLY (512 thr, 8 waves, 2 blocks/CU, no
// manual pipeline, no carried state — R2/R3's carried float4s went to
// scratch and regressed; reverted).  ONE mechanism change vs R1:
//   BIAS-AS-C: 8 persistent f32x4 bias splats (bsp[nt]) are passed directly
//   as the C operand of the first MFMA of each acc chain, eliminating the
//   128 v_mov acc-init per p2 (~16% of VALU instrs).  Requires static
//   indexing of bsp[] -> nt loop fully unrolled (rule #20: runtime-indexed
//   ext_vector arrays go to scratch).
// ---------------------------------------------------------------------------
__global__ __launch_bounds__(512, 4) void DensityAwareFeatureAggregator_main(
    const float4* __restrict__ pts4,      // (B*N) padded, global index
    const _Float16* __restrict__ feat16,  // (B*N,32) f16
    const int*   __restrict__ nbr,        // (B,N,32)
    const float* __restrict__ pe_w1,      // (3,64)
    const float* __restrict__ pe_b1,      // (64)
    const float* __restrict__ b1c,        // (128) fused bias
    const _Float16* __restrict__ gB1,     // W1c frags (24 tiles)
    const _Float16* __restrict__ gW2,     // W2 frags (16 tiles, pre-scaled /32)
    const float* __restrict__ b2g,        // (64)
    float* __restrict__ out)              // (B,N,64)
{
    __shared__ __align__(16) _Float16 sB1[24 * 512];     // 24576 B (8-wave shared)
    __shared__ __align__(16) f16x8    sTabH[32];         //   512 B
    __shared__ __align__(16) ushort4  sRI[8][64];        //  4096 B
    __shared__ __align__(16) _Float16 sHM[8][16 * 136];  // 34816 B
    // total 64000 B -> 2 blocks/CU, 16 waves/CU

    const int t = threadIdx.x;
    {
        const uint4* g = (const uint4*)gB1;
        uint4* d = (uint4*)sB1;
        for (int i = t; i < 1536; i += 512) d[i] = g[i];
    }
    if (t < 32) {   // col-pair tables: {x0,x1,y0,y1,z0,z1,b0,b1}
        int cp = t;
        f16x8 e;
        e[0] = (_Float16)pe_w1[2 * cp];       e[1] = (_Float16)pe_w1[2 * cp + 1];
        e[2] = (_Float16)pe_w1[64 + 2 * cp];  e[3] = (_Float16)pe_w1[64 + 2 * cp + 1];
        e[4] = (_Float16)pe_w1[128 + 2 * cp]; e[5] = (_Float16)pe_w1[128 + 2 * cp + 1];
        e[6] = (_Float16)pe_b1[2 * cp];       e[7] = (_Float16)pe_b1[2 * cp + 1];
        sTabH[cp] = e;
    }
    __syncthreads();

    const int w = t >> 6, l = t & 63, q = l >> 4, c16 = l & 15;
    // 512 blocks: XCD-swizzled bijective mapping (bid&7 = XCD, 64 blocks each)
    const int nb   = (blockIdx.x & 7) * 64 + (blockIdx.x >> 3);
    const int base = (nb * 8 + w) * 16;
    const int bo   = base & ~(NN - 1);   // batch offset into flat point ids

    f16x8 tab1[4], tab2[4];
#pragma unroll
    for (int u = 0; u < 4; ++u) {
        tab1[u] = sTabH[q * 4 + u];
        tab2[u] = sTabH[16 + q * 4 + u];
    }
    // BIAS-AS-C: persistent splat quads, used directly as MFMA C operands.
    // (+32 VGPR, cap 128 at 2 blocks/CU — occupancy is LDS-bound, safe.)
    f32x4 bsp[8];
#pragma unroll
    for (int nt = 0; nt < 8; ++nt) {
        float bv = b1c[nt * 16 + c16];
        f32x4 z; z[0] = z[1] = z[2] = z[3] = bv;
        bsp[nt] = z;
    }

    const f16x8* B1f = (const f16x8*)sB1;
    _Float16* hmw = &sHM[w][0];

#pragma unroll 1
    for (int p2 = 0; p2 < 8; ++p2) {
        const int mA = base + 2 * p2;
        // ---- full-wave staging: lanes 0-31 point A, 32-63 point B ----
        int idx = nbr[(size_t)mA * KK + l];
        float4 pc = pts4[mA + (l >> 5)];
        float4 pn = pts4[bo + idx];
        ushort4 st;
        st.x = h2u((_Float16)(pn.x - pc.x));
        st.y = h2u((_Float16)(pn.y - pc.y));
        st.z = h2u((_Float16)(pn.z - pc.z));
        st.w = (unsigned short)idx;
        sRI[w][l] = st;
        ushort4 eA0 = sRI[w][c16];
        ushort4 eA1 = sRI[w][16 + c16];
        ushort4 eB0 = sRI[w][32 + c16];
        ushort4 eB1 = sRI[w][48 + c16];

        // ---- feature A-frags from fp16 global (MFMA A layout) ----
        f16x8 afA0 = ((const f16x8*)(feat16 + ((size_t)(bo + eA0.w)) * 32))[q];
        f16x8 afA1 = ((const f16x8*)(feat16 + ((size_t)(bo + eA1.w)) * 32))[q];
        f16x8 afB0 = ((const f16x8*)(feat16 + ((size_t)(bo + eB0.w)) * 32))[q];
        f16x8 afB1 = ((const f16x8*)(feat16 + ((size_t)(bo + eB1.w)) * 32))[q];

        // ---- pe A-frags: array-free, packed f16x2 math ----
        f16x8 apA10, apA20, apA11, apA21, apB10, apB20, apB11, apB21;
        PE_FRAGS(eA0, apA10, apA20);
        PE_FRAGS(eA1, apA11, apA21);
        PE_FRAGS(eB0, apB10, apB20);
        PE_FRAGS(eB1, apB11, apB21);

        // ---- per-N-tile: 3 shared B-frags, 12 MFMAs, reduce ----
        // FULLY unrolled: bsp[nt] static index (rule #20), zero acc-init movs.
#pragma unroll
        for (int nt = 0; nt < 8; ++nt) {
            f16x8 bf0 = B1f[nt * 64 + l];
            f16x8 bf1 = B1f[(8 + nt) * 64 + l];
            f16x8 bf2 = B1f[(16 + nt) * 64 + l];
            f32x4 aA0 = __builtin_amdgcn_mfma_f32_16x16x32_f16(afA0,  bf0, bsp[nt], 0, 0, 0);
            f32x4 aA1 = __builtin_amdgcn_mfma_f32_16x16x32_f16(afA1,  bf0, bsp[nt], 0, 0, 0);
            f32x4 aB0 = __builtin_amdgcn_mfma_f32_16x16x32_f16(afB0,  bf0, bsp[nt], 0, 0, 0);
            f32x4 aB1 = __builtin_amdgcn_mfma_f32_16x16x32_f16(afB1,  bf0, bsp[nt], 0, 0, 0);
            aA0 = __builtin_amdgcn_mfma_f32_16x16x32_f16(apA10, bf1, aA0, 0, 0, 0);
            aA1 = __builtin_amdgcn_mfma_f32_16x16x32_f16(apA11, bf1, aA1, 0, 0, 0);
            aB0 = __builtin_amdgcn_mfma_f32_16x16x32_f16(apB10, bf1, aB0, 0, 0, 0);
            aB1 = __builtin_amdgcn_mfma_f32_16x16x32_f16(apB11, bf1, aB1, 0, 0, 0);
            aA0 = __builtin_amdgcn_mfma_f32_16x16x32_f16(apA20, bf2, aA0, 0, 0, 0);
            aA1 = __builtin_amdgcn_mfma_f32_16x16x32_f16(apA21, bf2, aA1, 0, 0, 0);
            aB0 = __builtin_amdgcn_mfma_f32_16x16x32_f16(apB20, bf2, aB0, 0, 0, 0);
            aB1 = __builtin_amdgcn_mfma_f32_16x16x32_f16(apB21, bf2, aB1, 0, 0, 0);

            float sA = fmaxf(aA0[0], 0.f) + fmaxf(aA0[1], 0.f)
                     + fmaxf(aA0[2], 0.f) + fmaxf(aA0[3], 0.f)
                     + fmaxf(aA1[0], 0.f) + fmaxf(aA1[1], 0.f)
                     + fmaxf(aA1[2], 0.f) + fmaxf(aA1[3], 0.f);
            float sB = fmaxf(aB0[0], 0.f) + fmaxf(aB0[1], 0.f)
                     + fmaxf(aB0[2], 0.f) + fmaxf(aB0[3], 0.f)
                     + fmaxf(aB1[0], 0.f) + fmaxf(aB1[1], 0.f)
                     + fmaxf(aB1[2], 0.f) + fmaxf(aB1[3], 0.f);
            sA += __shfl_xor(sA, 16, 64);
            sA += __shfl_xor(sA, 32, 64);
            sB += __shfl_xor(sB, 16, 64);
            sB += __shfl_xor(sB, 32, 64);
            if (q == 0) {
                hmw[(2 * p2) * 136 + nt * 16 + c16]     = (_Float16)sA;
                hmw[(2 * p2 + 1) * 136 + nt * 16 + c16] = (_Float16)sB;
            }
        }
    }

    // ---- epilogue: OUT(16x64) = HM(16x128) @ W2s + b2 (verified R2-R7) ----
    const f16x8* W2f = (const f16x8*)gW2;
    f32x4 acc2[4];
#pragma unroll
    for (int nt = 0; nt < 4; ++nt) {
        f32x4 z; float bv = b2g[nt * 16 + c16];
        z[0] = z[1] = z[2] = z[3] = bv;
        acc2[nt] = z;
    }
#pragma unroll
    for (int ks = 0; ks < 4; ++ks) {
        f16x8 a2 = *(const f16x8*)&hmw[c16 * 136 + ks * 32 + q * 8];
#pragma unroll
        for (int nt = 0; nt < 4; ++nt) {
            f16x8 bf = W2f[(ks * 4 + nt) * 64 + l];
            acc2[nt] = __builtin_amdgcn_mfma_f32_16x16x32_f16(a2, bf, acc2[nt], 0, 0, 0);
        }
    }
#pragma unroll
    for (int nt = 0; nt < 4; ++nt)
#pragma unroll
        for (int r = 0; r < 4; ++r)
            out[(size_t)(base + q * 4 + r) * OUTF + nt * 16 + c16] = acc2[nt][r];
}

// ---------------------------------------------------------------------------
extern "C" void kernel_launch(void* const* d_in, const int* in_sizes, int n_in,
                              void* d_out, int out_size, void* d_ws, size_t ws_size,
                              hipStream_t stream)
{
    const float* points   = (const float*)d_in[0];
    const float* features = (const float*)d_in[1];
    // d_in[2] density: provably unused (softmax over K identical values = 1/K)
    const int*   nbr      = (const int*)d_in[3];
    const float* pe_w1    = (const float*)d_in[4];
    const float* pe_b1    = (const float*)d_in[5];
    const float* pe_w2    = (const float*)d_in[6];
    const float* pe_b2    = (const float*)d_in[7];
    const float* mlp_w1   = (const float*)d_in[8];
    const float* mlp_b1   = (const float*)d_in[9];
    const float* mlp_w2   = (const float*)d_in[10];
    const float* mlp_b2   = (const float*)d_in[11];

    float* wsf = (float*)d_ws;
    float*    b1c    = wsf;                         // 128 f32
    _Float16* gB1    = (_Float16*)(wsf + 128);      // 12288 f16
    _Float16* gW2    = (_Float16*)(wsf + 6272);     // 8192 f16
    float4*   pts4   = (float4*)(wsf + 10368);      // 65536 float4
    _Float16* feat16 = (_Float16*)(wsf + 272512);   // 2097152 f16

    prep_all<<<2345, 256, 0, stream>>>(
        pe_w2, pe_b2, mlp_w1, mlp_b1, mlp_w2, features, points,
        gB1, gW2, b1c, feat16, pts4);

    DensityAwareFeatureAggregator_main<<<512, 512, 0, stream>>>(
        pts4, feat16, nbr, pe_w1, pe_b1, b1c, gB1, gW2, mlp_b2,
        (float*)d_out);
}

// Round 6
// 183.037 us; speedup vs baseline: 1.7112x; 1.7112x over previous
//
#include <hip/hip_runtime.h>

#define BB   4
#define NN   16384
#define KK   32
#define HID  128
#define OUTF 64

// prep_v2 grid: 40 weight blocks + (rel4 2,097,152 + feat16 524,288)/256
// = 40 + 10,240 work blocks, + 1 b1c block at the end.
#define PREP_WORK_BLOCKS 10240
#define PREP_GRID        (40 + PREP_WORK_BLOCKS + 1)
#define PREP_B1C_BID     (40 + PREP_WORK_BLOCKS)

typedef _Float16 f16x8 __attribute__((ext_vector_type(8)));
typedef _Float16 f16x4 __attribute__((ext_vector_type(4)));
typedef _Float16 f16x2 __attribute__((ext_vector_type(2)));
typedef float    f32x4 __attribute__((ext_vector_type(4)));

static __device__ __forceinline__ unsigned short h2u(_Float16 h) {
    union { _Float16 h; unsigned short u; } c; c.h = h; return c.u;
}
static __device__ __forceinline__ _Float16 u2h(unsigned short u) {
    union { _Float16 h; unsigned short u; } c; c.u = u; return c.h;
}

// pe column-pair MAC: v = bias2 + t.xy*rx + t.zw*ry + t[4:5]*rz  (v_pk_fma_f16)
#define PE_HALF(T, RX, RY, RZ)                                              \
    (__builtin_shufflevector((T), (T), 6, 7)                                \
     + __builtin_shufflevector((T), (T), 0, 1) * (RX)                       \
     + __builtin_shufflevector((T), (T), 2, 3) * (RY)                       \
     + __builtin_shufflevector((T), (T), 4, 5) * (RZ))

// Array-free pe fragment builder: named temporaries only, relu via pk_max,
// f16x8 assembly via shufflevector (register placement, no insert chains).
#define PE_FRAGS(E, O1, O2)                                                 \
    do {                                                                    \
        _Float16 _hx = u2h((E).x), _hy = u2h((E).y), _hz = u2h((E).z);      \
        f16x2 _rx = { _hx, _hx }, _ry = { _hy, _hy }, _rz = { _hz, _hz };   \
        f16x2 _z = { (_Float16)0.f, (_Float16)0.f };                        \
        f16x2 _a0 = __builtin_elementwise_max(PE_HALF(tab1[0], _rx, _ry, _rz), _z); \
        f16x2 _a1 = __builtin_elementwise_max(PE_HALF(tab1[1], _rx, _ry, _rz), _z); \
        f16x2 _a2 = __builtin_elementwise_max(PE_HALF(tab1[2], _rx, _ry, _rz), _z); \
        f16x2 _a3 = __builtin_elementwise_max(PE_HALF(tab1[3], _rx, _ry, _rz), _z); \
        f16x2 _b0 = __builtin_elementwise_max(PE_HALF(tab2[0], _rx, _ry, _rz), _z); \
        f16x2 _b1 = __builtin_elementwise_max(PE_HALF(tab2[1], _rx, _ry, _rz), _z); \
        f16x2 _b2 = __builtin_elementwise_max(PE_HALF(tab2[2], _rx, _ry, _rz), _z); \
        f16x2 _b3 = __builtin_elementwise_max(PE_HALF(tab2[3], _rx, _ry, _rz), _z); \
        f16x4 _al = __builtin_shufflevector(_a0, _a1, 0, 1, 2, 3);          \
        f16x4 _ah = __builtin_shufflevector(_a2, _a3, 0, 1, 2, 3);          \
        f16x4 _bl = __builtin_shufflevector(_b0, _b1, 0, 1, 2, 3);          \
        f16x4 _bh = __builtin_shufflevector(_b2, _b3, 0, 1, 2, 3);          \
        O1 = __builtin_shufflevector(_al, _ah, 0, 1, 2, 3, 4, 5, 6, 7);     \
        O2 = __builtin_shufflevector(_bl, _bh, 0, 1, 2, 3, 4, 5, 6, 7);     \
    } while (0)

// ---------------------------------------------------------------------------
// prep_v2: weights pack + feat fp32->f16 + rel4 precompute.
// rel4[t] for t=(b*N+n)*32+k packs {dx,dy,dz (f16), idx (u16)} — the entire
// gather/convert/LDS-transpose staging chain of the main loop, done once in
// a fully-parallel memory-bound kernel where latency is hidden by TLP.
// blocks 0..23        : gB1 tile pack (24 tiles)
// blocks 24..39       : gW2 tile pack (16 tiles, pre-scaled 1/32)
// blocks 40..10279    : rel4 (2,097,152 thr) then feat16 (524,288 thr)
// block  10280        : b1c = mlp_b1 + pe_b2 @ W1b
// ---------------------------------------------------------------------------
__global__ __launch_bounds__(256) void prep_v2(
    const float* __restrict__ pe_w2, const float* __restrict__ pe_b2,
    const float* __restrict__ mlp_w1, const float* __restrict__ mlp_b1,
    const float* __restrict__ mlp_w2,
    const float* __restrict__ features, const float* __restrict__ points,
    const int* __restrict__ nbr,
    _Float16* __restrict__ gB1, _Float16* __restrict__ gW2,
    float* __restrict__ b1c,
    _Float16* __restrict__ feat16, ushort4* __restrict__ rel4)
{
    const int bid = blockIdx.x, tid = threadIdx.x;
    if (bid >= 40) {
        if (bid == PREP_B1C_BID) {
            if (tid < HID) {
                float a = mlp_b1[tid];
#pragma unroll 16
                for (int c = 0; c < 64; ++c)
                    a = fmaf(pe_b2[c], mlp_w1[(32 + c) * HID + tid], a);
                b1c[tid] = a;
            }
            return;
        }
        int t = (bid - 40) * 256 + tid;
        if (t < BB * NN * KK) {          // rel4: one thread per (point,k)
            int idx = nbr[t];
            int pt  = t >> 5;
            int bo  = pt & ~(NN - 1);
            const float* pc = points + (size_t)pt * 3;
            const float* pn = points + (size_t)(bo + idx) * 3;
            ushort4 st;
            st.x = h2u((_Float16)(pn[0] - pc[0]));
            st.y = h2u((_Float16)(pn[1] - pc[1]));
            st.z = h2u((_Float16)(pn[2] - pc[2]));
            st.w = (unsigned short)idx;
            rel4[t] = st;
        } else {
            int u = t - BB * NN * KK;
            if (u < BB * NN * 8) {       // feat fp32 -> f16 (float4 units)
                float4 v = ((const float4*)features)[u];
                f16x4 h;
                h[0] = (_Float16)v.x; h[1] = (_Float16)v.y;
                h[2] = (_Float16)v.z; h[3] = (_Float16)v.w;
                *(f16x4*)(feat16 + (size_t)u * 4) = h;
            }
        }
        return;
    }
    if (bid < 24) {   // gB1: tile (ks,nt); element e: l=e>>3, j=e&7
        int ks = bid >> 3, nt = bid & 7;
        for (int e = tid; e < 512; e += 256) {
            int l = e >> 3, j = e & 7;
            int k = ks * 32 + (l >> 4) * 8 + j;
            int n = nt * 16 + (l & 15);
            float v;
            if (k < 32) {
                v = mlp_w1[k * HID + n];
            } else {
                int r = k - 32;
                v = 0.f;
#pragma unroll 16
                for (int c = 0; c < 64; ++c)
                    v = fmaf(pe_w2[r * 64 + c], mlp_w1[(32 + c) * HID + n], v);
            }
            gB1[bid * 512 + e] = (_Float16)v;
        }
    } else {          // gW2 — pre-scaled by 1/32 so hm stores skip the mean mul
        int tb = bid - 24;
        int ks = tb >> 2, nt = tb & 3;
        for (int e = tid; e < 512; e += 256) {
            int l = e >> 3, j = e & 7;
            int k = ks * 32 + (l >> 4) * 8 + j;
            int n = nt * 16 + (l & 15);
            gW2[tb * 512 + e] = (_Float16)(mlp_w2[k * OUTF + n] * 0.03125f);
        }
    }
}

// ---------------------------------------------------------------------------
// Main v2: R1-champion structure EXACTLY (512 thr, 8 waves, 2 blocks/CU, nt
// loop unroll 2, per-iteration bias splat — proven no-spill at 64 VGPR).
// ONE change: staging chain replaced by 4 direct 8B broadcast loads from the
// precomputed rel4 (addresses affine in p2, no dependent gather hop, no f16
// converts, no sRI LDS round-trip). Live state strictly SMALLER than R1.
// ---------------------------------------------------------------------------
__global__ __launch_bounds__(512, 4) void DensityAwareFeatureAggregator_main(
    const ushort4* __restrict__ rel4,     // (B*N,32) {dx,dy,dz,idx}
    const _Float16* __restrict__ feat16,  // (B*N,32) f16
    const float* __restrict__ pe_w1,      // (3,64)
    const float* __restrict__ pe_b1,      // (64)
    const float* __restrict__ b1c,        // (128) fused bias
    const _Float16* __restrict__ gB1,     // W1c frags (24 tiles)
    const _Float16* __restrict__ gW2,     // W2 frags (16 tiles, pre-scaled /32)
    const float* __restrict__ b2g,        // (64)
    float* __restrict__ out)              // (B,N,64)
{
    __shared__ __align__(16) _Float16 sB1[24 * 512];     // 24576 B
    __shared__ __align__(16) f16x8    sTabH[32];         //   512 B
    __shared__ __align__(16) _Float16 sHM[8][16 * 136];  // 34816 B
    // total 59904 B -> 2 blocks/CU, 16 waves/CU

    const int t = threadIdx.x;
    {
        const uint4* g = (const uint4*)gB1;
        uint4* d = (uint4*)sB1;
        for (int i = t; i < 1536; i += 512) d[i] = g[i];
    }
    if (t < 32) {   // col-pair tables: {x0,x1,y0,y1,z0,z1,b0,b1}
        int cp = t;
        f16x8 e;
        e[0] = (_Float16)pe_w1[2 * cp];       e[1] = (_Float16)pe_w1[2 * cp + 1];
        e[2] = (_Float16)pe_w1[64 + 2 * cp];  e[3] = (_Float16)pe_w1[64 + 2 * cp + 1];
        e[4] = (_Float16)pe_w1[128 + 2 * cp]; e[5] = (_Float16)pe_w1[128 + 2 * cp + 1];
        e[6] = (_Float16)pe_b1[2 * cp];       e[7] = (_Float16)pe_b1[2 * cp + 1];
        sTabH[cp] = e;
    }
    __syncthreads();

    const int w = t >> 6, l = t & 63, q = l >> 4, c16 = l & 15;
    // 512 blocks: XCD-swizzled bijective mapping (bid&7 = XCD, 64 blocks each)
    const int nb   = (blockIdx.x & 7) * 64 + (blockIdx.x >> 3);
    const int base = (nb * 8 + w) * 16;
    const int bo   = base & ~(NN - 1);   // batch offset into flat point ids

    f16x8 tab1[4], tab2[4];
#pragma unroll
    for (int u = 0; u < 4; ++u) {
        tab1[u] = sTabH[q * 4 + u];
        tab2[u] = sTabH[16 + q * 4 + u];
    }
    float bias1[8];
#pragma unroll
    for (int nt = 0; nt < 8; ++nt) bias1[nt] = b1c[nt * 16 + c16];

    const f16x8* B1f = (const f16x8*)sB1;
    _Float16* hmw = &sHM[w][0];

#pragma unroll 1
    for (int p2 = 0; p2 < 8; ++p2) {
        const int mA = base + 2 * p2;
        // ---- staging: 4 direct 8B broadcast loads (no chain, no LDS) ----
        const ushort4* rg = rel4 + (size_t)mA * KK;
        ushort4 eA0 = rg[c16];
        ushort4 eA1 = rg[16 + c16];
        ushort4 eB0 = rg[32 + c16];
        ushort4 eB1 = rg[48 + c16];

        // ---- feature A-frags from fp16 global (MFMA A layout) ----
        f16x8 afA0 = ((const f16x8*)(feat16 + ((size_t)(bo + eA0.w)) * 32))[q];
        f16x8 afA1 = ((const f16x8*)(feat16 + ((size_t)(bo + eA1.w)) * 32))[q];
        f16x8 afB0 = ((const f16x8*)(feat16 + ((size_t)(bo + eB0.w)) * 32))[q];
        f16x8 afB1 = ((const f16x8*)(feat16 + ((size_t)(bo + eB1.w)) * 32))[q];

        // ---- pe A-frags: array-free, packed f16x2 math ----
        f16x8 apA10, apA20, apA11, apA21, apB10, apB20, apB11, apB21;
        PE_FRAGS(eA0, apA10, apA20);
        PE_FRAGS(eA1, apA11, apA21);
        PE_FRAGS(eB0, apB10, apB20);
        PE_FRAGS(eB1, apB11, apB21);

        // ---- per-N-tile: 3 shared B-frags, 12 MFMAs, reduce ----
#pragma unroll 2
        for (int nt = 0; nt < 8; ++nt) {
            f16x8 bf0 = B1f[nt * 64 + l];
            f16x8 bf1 = B1f[(8 + nt) * 64 + l];
            f16x8 bf2 = B1f[(16 + nt) * 64 + l];
            f32x4 aA0, aA1, aB0, aB1;
            aA0[0] = aA0[1] = aA0[2] = aA0[3] = bias1[nt];
            aA1 = aA0; aB0 = aA0; aB1 = aA0;
            aA0 = __builtin_amdgcn_mfma_f32_16x16x32_f16(afA0,  bf0, aA0, 0, 0, 0);
            aA1 = __builtin_amdgcn_mfma_f32_16x16x32_f16(afA1,  bf0, aA1, 0, 0, 0);
            aB0 = __builtin_amdgcn_mfma_f32_16x16x32_f16(afB0,  bf0, aB0, 0, 0, 0);
            aB1 = __builtin_amdgcn_mfma_f32_16x16x32_f16(afB1,  bf0, aB1, 0, 0, 0);
            aA0 = __builtin_amdgcn_mfma_f32_16x16x32_f16(apA10, bf1, aA0, 0, 0, 0);
            aA1 = __builtin_amdgcn_mfma_f32_16x16x32_f16(apA11, bf1, aA1, 0, 0, 0);
            aB0 = __builtin_amdgcn_mfma_f32_16x16x32_f16(apB10, bf1, aB0, 0, 0, 0);
            aB1 = __builtin_amdgcn_mfma_f32_16x16x32_f16(apB11, bf1, aB1, 0, 0, 0);
            aA0 = __builtin_amdgcn_mfma_f32_16x16x32_f16(apA20, bf2, aA0, 0, 0, 0);
            aA1 = __builtin_amdgcn_mfma_f32_16x16x32_f16(apA21, bf2, aA1, 0, 0, 0);
            aB0 = __builtin_amdgcn_mfma_f32_16x16x32_f16(apB20, bf2, aB0, 0, 0, 0);
            aB1 = __builtin_amdgcn_mfma_f32_16x16x32_f16(apB21, bf2, aB1, 0, 0, 0);

            float sA = fmaxf(aA0[0], 0.f) + fmaxf(aA0[1], 0.f)
                     + fmaxf(aA0[2], 0.f) + fmaxf(aA0[3], 0.f)
                     + fmaxf(aA1[0], 0.f) + fmaxf(aA1[1], 0.f)
                     + fmaxf(aA1[2], 0.f) + fmaxf(aA1[3], 0.f);
            float sB = fmaxf(aB0[0], 0.f) + fmaxf(aB0[1], 0.f)
                     + fmaxf(aB0[2], 0.f) + fmaxf(aB0[3], 0.f)
                     + fmaxf(aB1[0], 0.f) + fmaxf(aB1[1], 0.f)
                     + fmaxf(aB1[2], 0.f) + fmaxf(aB1[3], 0.f);
            sA += __shfl_xor(sA, 16, 64);
            sA += __shfl_xor(sA, 32, 64);
            sB += __shfl_xor(sB, 16, 64);
            sB += __shfl_xor(sB, 32, 64);
            if (q == 0) {
                hmw[(2 * p2) * 136 + nt * 16 + c16]     = (_Float16)sA;
                hmw[(2 * p2 + 1) * 136 + nt * 16 + c16] = (_Float16)sB;
            }
        }
    }

    // ---- epilogue: OUT(16x64) = HM(16x128) @ W2s + b2 (verified R2-R7) ----
    const f16x8* W2f = (const f16x8*)gW2;
    f32x4 acc2[4];
#pragma unroll
    for (int nt = 0; nt < 4; ++nt) {
        f32x4 z; float bv = b2g[nt * 16 + c16];
        z[0] = z[1] = z[2] = z[3] = bv;
        acc2[nt] = z;
    }
#pragma unroll
    for (int ks = 0; ks < 4; ++ks) {
        f16x8 a2 = *(const f16x8*)&hmw[c16 * 136 + ks * 32 + q * 8];
#pragma unroll
        for (int nt = 0; nt < 4; ++nt) {
            f16x8 bf = W2f[(ks * 4 + nt) * 64 + l];
            acc2[nt] = __builtin_amdgcn_mfma_f32_16x16x32_f16(a2, bf, acc2[nt], 0, 0, 0);
        }
    }
#pragma unroll
    for (int nt = 0; nt < 4; ++nt)
#pragma unroll
        for (int r = 0; r < 4; ++r)
            out[(size_t)(base + q * 4 + r) * OUTF + nt * 16 + c16] = acc2[nt][r];
}

// ===========================================================================
// FALLBACK PATH (used only if ws_size < 21 MB): exact R1 champion kernels.
// ===========================================================================
__global__ __launch_bounds__(256) void prep_fb(
    const float* __restrict__ pe_w2, const float* __restrict__ pe_b2,
    const float* __restrict__ mlp_w1, const float* __restrict__ mlp_b1,
    const float* __restrict__ mlp_w2,
    const float* __restrict__ features, const float* __restrict__ points,
    _Float16* __restrict__ gB1, _Float16* __restrict__ gW2,
    float* __restrict__ b1c,
    _Float16* __restrict__ feat16, float4* __restrict__ pts4)
{
    const int bid = blockIdx.x, tid = threadIdx.x;
    if (bid >= 40) {
        if (bid == 2344) {
            if (tid < HID) {
                float a = mlp_b1[tid];
#pragma unroll 16
                for (int c = 0; c < 64; ++c)
                    a = fmaf(pe_b2[c], mlp_w1[(32 + c) * HID + tid], a);
                b1c[tid] = a;
            }
            return;
        }
        int t = (bid - 40) * 256 + tid;
        if (t < BB * NN * 8) {
            float4 v = ((const float4*)features)[t];
            f16x4 h;
            h[0] = (_Float16)v.x; h[1] = (_Float16)v.y;
            h[2] = (_Float16)v.z; h[3] = (_Float16)v.w;
            *(f16x4*)(feat16 + (size_t)t * 4) = h;
        } else {
            int i = t - BB * NN * 8;
            if (i < BB * NN) {
                const float* p = points + (size_t)i * 3;
                pts4[i] = make_float4(p[0], p[1], p[2], 0.f);
            }
        }
        return;
    }
    if (bid < 24) {
        int ks = bid >> 3, nt = bid & 7;
        for (int e = tid; e < 512; e += 256) {
            int l = e >> 3, j = e & 7;
            int k = ks * 32 + (l >> 4) * 8 + j;
            int n = nt * 16 + (l & 15);
            float v;
            if (k < 32) {
                v = mlp_w1[k * HID + n];
            } else {
                int r = k - 32;
                v = 0.f;
#pragma unroll 16
                for (int c = 0; c < 64; ++c)
                    v = fmaf(pe_w2[r * 64 + c], mlp_w1[(32 + c) * HID + n], v);
            }
            gB1[bid * 512 + e] = (_Float16)v;
        }
    } else {
        int tb = bid - 24;
        int ks = tb >> 2, nt = tb & 3;
        for (int e = tid; e < 512; e += 256) {
            int l = e >> 3, j = e & 7;
            int k = ks * 32 + (l >> 4) * 8 + j;
            int n = nt * 16 + (l & 15);
            gW2[tb * 512 + e] = (_Float16)(mlp_w2[k * OUTF + n] * 0.03125f);
        }
    }
}

__global__ __launch_bounds__(512, 4) void main_fb(
    const float4* __restrict__ pts4,
    const _Float16* __restrict__ feat16,
    const int*   __restrict__ nbr,
    const float* __restrict__ pe_w1,
    const float* __restrict__ pe_b1,
    const float* __restrict__ b1c,
    const _Float16* __restrict__ gB1,
    const _Float16* __restrict__ gW2,
    const float* __restrict__ b2g,
    float* __restrict__ out)
{
    __shared__ __align__(16) _Float16 sB1[24 * 512];
    __shared__ __align__(16) f16x8    sTabH[32];
    __shared__ __align__(16) ushort4  sRI[8][64];
    __shared__ __align__(16) _Float16 sHM[8][16 * 136];

    const int t = threadIdx.x;
    {
        const uint4* g = (const uint4*)gB1;
        uint4* d = (uint4*)sB1;
        for (int i = t; i < 1536; i += 512) d[i] = g[i];
    }
    if (t < 32) {
        int cp = t;
        f16x8 e;
        e[0] = (_Float16)pe_w1[2 * cp];       e[1] = (_Float16)pe_w1[2 * cp + 1];
        e[2] = (_Float16)pe_w1[64 + 2 * cp];  e[3] = (_Float16)pe_w1[64 + 2 * cp + 1];
        e[4] = (_Float16)pe_w1[128 + 2 * cp]; e[5] = (_Float16)pe_w1[128 + 2 * cp + 1];
        e[6] = (_Float16)pe_b1[2 * cp];       e[7] = (_Float16)pe_b1[2 * cp + 1];
        sTabH[cp] = e;
    }
    __syncthreads();

    const int w = t >> 6, l = t & 63, q = l >> 4, c16 = l & 15;
    const int nb   = (blockIdx.x & 7) * 64 + (blockIdx.x >> 3);
    const int base = (nb * 8 + w) * 16;
    const int bo   = base & ~(NN - 1);

    f16x8 tab1[4], tab2[4];
#pragma unroll
    for (int u = 0; u < 4; ++u) {
        tab1[u] = sTabH[q * 4 + u];
        tab2[u] = sTabH[16 + q * 4 + u];
    }
    float bias1[8];
#pragma unroll
    for (int nt = 0; nt < 8; ++nt) bias1[nt] = b1c[nt * 16 + c16];

    const f16x8* B1f = (const f16x8*)sB1;
    _Float16* hmw = &sHM[w][0];

#pragma unroll 1
    for (int p2 = 0; p2 < 8; ++p2) {
        const int mA = base + 2 * p2;
        int idx = nbr[(size_t)mA * KK + l];
        float4 pc = pts4[mA + (l >> 5)];
        float4 pn = pts4[bo + idx];
        ushort4 st;
        st.x = h2u((_Float16)(pn.x - pc.x));
        st.y = h2u((_Float16)(pn.y - pc.y));
        st.z = h2u((_Float16)(pn.z - pc.z));
        st.w = (unsigned short)idx;
        sRI[w][l] = st;
        ushort4 eA0 = sRI[w][c16];
        ushort4 eA1 = sRI[w][16 + c16];
        ushort4 eB0 = sRI[w][32 + c16];
        ushort4 eB1 = sRI[w][48 + c16];

        f16x8 afA0 = ((const f16x8*)(feat16 + ((size_t)(bo + eA0.w)) * 32))[q];
        f16x8 afA1 = ((const f16x8*)(feat16 + ((size_t)(bo + eA1.w)) * 32))[q];
        f16x8 afB0 = ((const f16x8*)(feat16 + ((size_t)(bo + eB0.w)) * 32))[q];
        f16x8 afB1 = ((const f16x8*)(feat16 + ((size_t)(bo + eB1.w)) * 32))[q];

        f16x8 apA10, apA20, apA11, apA21, apB10, apB20, apB11, apB21;
        PE_FRAGS(eA0, apA10, apA20);
        PE_FRAGS(eA1, apA11, apA21);
        PE_FRAGS(eB0, apB10, apB20);
        PE_FRAGS(eB1, apB11, apB21);

#pragma unroll 2
        for (int nt = 0; nt < 8; ++nt) {
            f16x8 bf0 = B1f[nt * 64 + l];
            f16x8 bf1 = B1f[(8 + nt) * 64 + l];
            f16x8 bf2 = B1f[(16 + nt) * 64 + l];
            f32x4 aA0, aA1, aB0, aB1;
            aA0[0] = aA0[1] = aA0[2] = aA0[3] = bias1[nt];
            aA1 = aA0; aB0 = aA0; aB1 = aA0;
            aA0 = __builtin_amdgcn_mfma_f32_16x16x32_f16(afA0,  bf0, aA0, 0, 0, 0);
            aA1 = __builtin_amdgcn_mfma_f32_16x16x32_f16(afA1,  bf0, aA1, 0, 0, 0);
            aB0 = __builtin_amdgcn_mfma_f32_16x16x32_f16(afB0,  bf0, aB0, 0, 0, 0);
            aB1 = __builtin_amdgcn_mfma_f32_16x16x32_f16(afB1,  bf0, aB1, 0, 0, 0);
            aA0 = __builtin_amdgcn_mfma_f32_16x16x32_f16(apA10, bf1, aA0, 0, 0, 0);
            aA1 = __builtin_amdgcn_mfma_f32_16x16x32_f16(apA11, bf1, aA1, 0, 0, 0);
            aB0 = __builtin_amdgcn_mfma_f32_16x16x32_f16(apB10, bf1, aB0, 0, 0, 0);
            aB1 = __builtin_amdgcn_mfma_f32_16x16x32_f16(apB11, bf1, aB1, 0, 0, 0);
            aA0 = __builtin_amdgcn_mfma_f32_16x16x32_f16(apA20, bf2, aA0, 0, 0, 0);
            aA1 = __builtin_amdgcn_mfma_f32_16x16x32_f16(apA21, bf2, aA1, 0, 0, 0);
            aB0 = __builtin_amdgcn_mfma_f32_16x16x32_f16(apB20, bf2, aB0, 0, 0, 0);
            aB1 = __builtin_amdgcn_mfma_f32_16x16x32_f16(apB21, bf2, aB1, 0, 0, 0);

            float sA = fmaxf(aA0[0], 0.f) + fmaxf(aA0[1], 0.f)
                     + fmaxf(aA0[2], 0.f) + fmaxf(aA0[3], 0.f)
                     + fmaxf(aA1[0], 0.f) + fmaxf(aA1[1], 0.f)
                     + fmaxf(aA1[2], 0.f) + fmaxf(aA1[3], 0.f);
            float sB = fmaxf(aB0[0], 0.f) + fmaxf(aB0[1], 0.f)
                     + fmaxf(aB0[2], 0.f) + fmaxf(aB0[3], 0.f)
                     + fmaxf(aB1[0], 0.f) + fmaxf(aB1[1], 0.f)
                     + fmaxf(aB1[2], 0.f) + fmaxf(aB1[3], 0.f);
            sA += __shfl_xor(sA, 16, 64);
            sA += __shfl_xor(sA, 32, 64);
            sB += __shfl_xor(sB, 16, 64);
            sB += __shfl_xor(sB, 32, 64);
            if (q == 0) {
                hmw[(2 * p2) * 136 + nt * 16 + c16]     = (_Float16)sA;
                hmw[(2 * p2 + 1) * 136 + nt * 16 + c16] = (_Float16)sB;
            }
        }
    }

    const f16x8* W2f = (const f16x8*)gW2;
    f32x4 acc2[4];
#pragma unroll
    for (int nt = 0; nt < 4; ++nt) {
        f32x4 z; float bv = b2g[nt * 16 + c16];
        z[0] = z[1] = z[2] = z[3] = bv;
        acc2[nt] = z;
    }
#pragma unroll
    for (int ks = 0; ks < 4; ++ks) {
        f16x8 a2 = *(const f16x8*)&hmw[c16 * 136 + ks * 32 + q * 8];
#pragma unroll
        for (int nt = 0; nt < 4; ++nt) {
            f16x8 bf = W2f[(ks * 4 + nt) * 64 + l];
            acc2[nt] = __builtin_amdgcn_mfma_f32_16x16x32_f16(a2, bf, acc2[nt], 0, 0, 0);
        }
    }
#pragma unroll
    for (int nt = 0; nt < 4; ++nt)
#pragma unroll
        for (int r = 0; r < 4; ++r)
            out[(size_t)(base + q * 4 + r) * OUTF + nt * 16 + c16] = acc2[nt][r];
}

// ---------------------------------------------------------------------------
extern "C" void kernel_launch(void* const* d_in, const int* in_sizes, int n_in,
                              void* d_out, int out_size, void* d_ws, size_t ws_size,
                              hipStream_t stream)
{
    const float* points   = (const float*)d_in[0];
    const float* features = (const float*)d_in[1];
    // d_in[2] density: provably unused (softmax over K identical values = 1/K)
    const int*   nbr      = (const int*)d_in[3];
    const float* pe_w1    = (const float*)d_in[4];
    const float* pe_b1    = (const float*)d_in[5];
    const float* pe_w2    = (const float*)d_in[6];
    const float* pe_b2    = (const float*)d_in[7];
    const float* mlp_w1   = (const float*)d_in[8];
    const float* mlp_b1   = (const float*)d_in[9];
    const float* mlp_w2   = (const float*)d_in[10];
    const float* mlp_b2   = (const float*)d_in[11];

    float* wsf = (float*)d_ws;

    // v2 layout (floats): b1c 128 | gB1 6144 | gW2 4096 | feat16 1,048,576 |
    //                     rel4 4,194,304  => 5,253,248 floats = 21,012,992 B
    const size_t need_v2 = (size_t)5253248 * 4;
    if (ws_size >= need_v2) {
        float*    b1c    = wsf;
        _Float16* gB1    = (_Float16*)(wsf + 128);
        _Float16* gW2    = (_Float16*)(wsf + 6272);
        _Float16* feat16 = (_Float16*)(wsf + 10368);
        ushort4*  rel4   = (ushort4*)(wsf + 1058944);

        prep_v2<<<PREP_GRID, 256, 0, stream>>>(
            pe_w2, pe_b2, mlp_w1, mlp_b1, mlp_w2, features, points, nbr,
            gB1, gW2, b1c, feat16, rel4);

        DensityAwareFeatureAggregator_main<<<512, 512, 0, stream>>>(
            rel4, feat16, pe_w1, pe_b1, b1c, gB1, gW2, mlp_b2,
            (float*)d_out);
    } else {
        // fallback: exact R1 champion path (5.3 MB workspace)
        float*    b1c    = wsf;
        _Float16* gB1    = (_Float16*)(wsf + 128);
        _Float16* gW2    = (_Float16*)(wsf + 6272);
        float4*   pts4   = (float4*)(wsf + 10368);
        _Float16* feat16 = (_Float16*)(wsf + 272512);

        prep_fb<<<2345, 256, 0, stream>>>(
            pe_w2, pe_b2, mlp_w1, mlp_b1, mlp_w2, features, points,
            gB1, gW2, b1c, feat16, pts4);

        main_fb<<<512, 512, 0, stream>>>(
            pts4, feat16, nbr, pe_w1, pe_b1, b1c, gB1, gW2, mlp_b2,
            (float*)d_out);
    }
}

// Round 8
// 178.425 us; speedup vs baseline: 1.7554x; 1.0258x over previous
//
#include <hip/hip_runtime.h>

#define BB   4
#define NN   16384
#define KK   32
#define HID  128
#define OUTF 64

typedef _Float16 f16x8 __attribute__((ext_vector_type(8)));
typedef _Float16 f16x4 __attribute__((ext_vector_type(4)));
typedef _Float16 f16x2 __attribute__((ext_vector_type(2)));
typedef float    f32x4 __attribute__((ext_vector_type(4)));

static __device__ __forceinline__ unsigned short h2u(_Float16 h) {
    union { _Float16 h; unsigned short u; } c; c.h = h; return c.u;
}
static __device__ __forceinline__ _Float16 u2h(unsigned short u) {
    union { _Float16 h; unsigned short u; } c; c.u = u; return c.h;
}

// pe column-pair MAC: v = bias2 + t.xy*rx + t.zw*ry + t[4:5]*rz  (v_pk_fma_f16)
#define PE_HALF(T, RX, RY, RZ)                                              \
    (__builtin_shufflevector((T), (T), 6, 7)                                \
     + __builtin_shufflevector((T), (T), 0, 1) * (RX)                       \
     + __builtin_shufflevector((T), (T), 2, 3) * (RY)                       \
     + __builtin_shufflevector((T), (T), 4, 5) * (RZ))

// Array-free pe fragment builder: named temporaries only, relu via pk_max,
// f16x8 assembly via shufflevector (register placement, no insert chains).
#define PE_FRAGS(E, O1, O2)                                                 \
    do {                                                                    \
        _Float16 _hx = u2h((E).x), _hy = u2h((E).y), _hz = u2h((E).z);      \
        f16x2 _rx = { _hx, _hx }, _ry = { _hy, _hy }, _rz = { _hz, _hz };   \
        f16x2 _z = { (_Float16)0.f, (_Float16)0.f };                        \
        f16x2 _a0 = __builtin_elementwise_max(PE_HALF(tab1[0], _rx, _ry, _rz), _z); \
        f16x2 _a1 = __builtin_elementwise_max(PE_HALF(tab1[1], _rx, _ry, _rz), _z); \
        f16x2 _a2 = __builtin_elementwise_max(PE_HALF(tab1[2], _rx, _ry, _rz), _z); \
        f16x2 _a3 = __builtin_elementwise_max(PE_HALF(tab1[3], _rx, _ry, _rz), _z); \
        f16x2 _b0 = __builtin_elementwise_max(PE_HALF(tab2[0], _rx, _ry, _rz), _z); \
        f16x2 _b1 = __builtin_elementwise_max(PE_HALF(tab2[1], _rx, _ry, _rz), _z); \
        f16x2 _b2 = __builtin_elementwise_max(PE_HALF(tab2[2], _rx, _ry, _rz), _z); \
        f16x2 _b3 = __builtin_elementwise_max(PE_HALF(tab2[3], _rx, _ry, _rz), _z); \
        f16x4 _al = __builtin_shufflevector(_a0, _a1, 0, 1, 2, 3);          \
        f16x4 _ah = __builtin_shufflevector(_a2, _a3, 0, 1, 2, 3);          \
        f16x4 _bl = __builtin_shufflevector(_b0, _b1, 0, 1, 2, 3);          \
        f16x4 _bh = __builtin_shufflevector(_b2, _b3, 0, 1, 2, 3);          \
        O1 = __builtin_shufflevector(_al, _ah, 0, 1, 2, 3, 4, 5, 6, 7);     \
        O2 = __builtin_shufflevector(_bl, _bh, 0, 1, 2, 3, 4, 5, 6, 7);     \
    } while (0)

// ---------------------------------------------------------------------------
// prep_all: R1 champion prep, unchanged (cheap path — no rel4).
// blocks 0..23   : gB1 tile pack (24 tiles, 16x16x32 B-layout)
// blocks 24..39  : gW2 tile pack (16 tiles), pre-scaled by 1/32 (mean fold)
// blocks 40..2343: feat fp32->fp16 + points->float4
// block  2344    : b1c = mlp_b1 + pe_b2 @ W1b
// ---------------------------------------------------------------------------
__global__ __launch_bounds__(256) void prep_all(
    const float* __restrict__ pe_w2, const float* __restrict__ pe_b2,
    const float* __restrict__ mlp_w1, const float* __restrict__ mlp_b1,
    const float* __restrict__ mlp_w2,
    const float* __restrict__ features, const float* __restrict__ points,
    _Float16* __restrict__ gB1, _Float16* __restrict__ gW2,
    float* __restrict__ b1c,
    _Float16* __restrict__ feat16, float4* __restrict__ pts4)
{
    const int bid = blockIdx.x, tid = threadIdx.x;
    if (bid >= 40) {
        if (bid == 2344) {
            if (tid < HID) {
                float a = mlp_b1[tid];
#pragma unroll 16
                for (int c = 0; c < 64; ++c)
                    a = fmaf(pe_b2[c], mlp_w1[(32 + c) * HID + tid], a);
                b1c[tid] = a;
            }
            return;
        }
        int t = (bid - 40) * 256 + tid;
        if (t < BB * NN * 8) {
            float4 v = ((const float4*)features)[t];
            f16x4 h;
            h[0] = (_Float16)v.x; h[1] = (_Float16)v.y;
            h[2] = (_Float16)v.z; h[3] = (_Float16)v.w;
            *(f16x4*)(feat16 + (size_t)t * 4) = h;
        } else {
            int i = t - BB * NN * 8;
            if (i < BB * NN) {
                const float* p = points + (size_t)i * 3;
                pts4[i] = make_float4(p[0], p[1], p[2], 0.f);
            }
        }
        return;
    }
    if (bid < 24) {   // gB1: tile (ks,nt); element e: l=e>>3, j=e&7
        int ks = bid >> 3, nt = bid & 7;
        for (int e = tid; e < 512; e += 256) {
            int l = e >> 3, j = e & 7;
            int k = ks * 32 + (l >> 4) * 8 + j;
            int n = nt * 16 + (l & 15);
            float v;
            if (k < 32) {
                v = mlp_w1[k * HID + n];
            } else {
                int r = k - 32;
                v = 0.f;
#pragma unroll 16
                for (int c = 0; c < 64; ++c)
                    v = fmaf(pe_w2[r * 64 + c], mlp_w1[(32 + c) * HID + n], v);
            }
            gB1[bid * 512 + e] = (_Float16)v;
        }
    } else {          // gW2 — pre-scaled by 1/32 so hm stores skip the mean mul
        int tb = bid - 24;
        int ks = tb >> 2, nt = tb & 3;
        for (int e = tid; e < 512; e += 256) {
            int l = e >> 3, j = e & 7;
            int k = ks * 32 + (l >> 4) * 8 + j;
            int n = nt * 16 + (l & 15);
            gW2[tb * 512 + e] = (_Float16)(mlp_w2[k * OUTF + n] * 0.03125f);
        }
    }
}

// ---------------------------------------------------------------------------
// k1 (main): R1 champion inner loop, UNCHANGED per-lane math. Structural
// change for occupancy: the W2 epilogue (and its 35 KB sHM) moves to a
// second kernel. hm (f16, 65536x128 = 16,777,216 B) is written to d_out
// (65536x64 f32 = same byte size — exact overlay, zero extra workspace).
//   LDS: sB1 24576 + sTab 512 + sRI 4096 = 29184 B
//   -> 4 blocks/CU (grid 1024 of 512 thr) = 32 waves/CU at VGPR<=64
//   (was 16 waves/CU with sHM; TLP doubles to fill the ~40% idle cycles).
// Each wave: 8 points, p2 loop of 4.
// ---------------------------------------------------------------------------
__global__ __launch_bounds__(512, 4) void DensityAwareFeatureAggregator_main(
    const float4* __restrict__ pts4,      // (B*N) padded, global index
    const _Float16* __restrict__ feat16,  // (B*N,32) f16
    const int*   __restrict__ nbr,        // (B,N,32)
    const float* __restrict__ pe_w1,      // (3,64)
    const float* __restrict__ pe_b1,      // (64)
    const float* __restrict__ b1c,        // (128) fused bias
    const _Float16* __restrict__ gB1,     // W1c frags (24 tiles)
    _Float16* __restrict__ hmG)           // hm out: (B*N,128) f16 (= d_out)
{
    __shared__ __align__(16) _Float16 sB1[24 * 512];     // 24576 B
    __shared__ __align__(16) f16x8    sTabH[32];         //   512 B
    __shared__ __align__(16) ushort4  sRI[8][64];        //  4096 B
    // total 29184 B -> 5 blocks/CU LDS-wise; grid gives 4/CU = 32 waves/CU

    const int t = threadIdx.x;
    {
        const uint4* g = (const uint4*)gB1;
        uint4* d = (uint4*)sB1;
        for (int i = t; i < 1536; i += 512) d[i] = g[i];
    }
    if (t < 32) {   // col-pair tables: {x0,x1,y0,y1,z0,z1,b0,b1}
        int cp = t;
        f16x8 e;
        e[0] = (_Float16)pe_w1[2 * cp];       e[1] = (_Float16)pe_w1[2 * cp + 1];
        e[2] = (_Float16)pe_w1[64 + 2 * cp];  e[3] = (_Float16)pe_w1[64 + 2 * cp + 1];
        e[4] = (_Float16)pe_w1[128 + 2 * cp]; e[5] = (_Float16)pe_w1[128 + 2 * cp + 1];
        e[6] = (_Float16)pe_b1[2 * cp];       e[7] = (_Float16)pe_b1[2 * cp + 1];
        sTabH[cp] = e;
    }
    __syncthreads();

    const int w = t >> 6, l = t & 63, q = l >> 4, c16 = l & 15;
    // 1024 blocks: XCD-swizzled bijective mapping (bid&7 = XCD, 128 each)
    const int nb   = (blockIdx.x & 7) * 128 + (blockIdx.x >> 3);
    const int base = (nb * 8 + w) * 8;   // 8 points per wave
    const int bo   = base & ~(NN - 1);   // batch offset into flat point ids

    f16x8 tab1[4], tab2[4];
#pragma unroll
    for (int u = 0; u < 4; ++u) {
        tab1[u] = sTabH[q * 4 + u];
        tab2[u] = sTabH[16 + q * 4 + u];
    }
    float bias1[8];
#pragma unroll
    for (int nt = 0; nt < 8; ++nt) bias1[nt] = b1c[nt * 16 + c16];

    const f16x8* B1f = (const f16x8*)sB1;

#pragma unroll 1
    for (int p2 = 0; p2 < 4; ++p2) {
        const int mA = base + 2 * p2;
        // ---- full-wave staging: lanes 0-31 point A, 32-63 point B ----
        int idx = nbr[(size_t)mA * KK + l];
        float4 pc = pts4[mA + (l >> 5)];
        float4 pn = pts4[bo + idx];
        ushort4 st;
        st.x = h2u((_Float16)(pn.x - pc.x));
        st.y = h2u((_Float16)(pn.y - pc.y));
        st.z = h2u((_Float16)(pn.z - pc.z));
        st.w = (unsigned short)idx;
        sRI[w][l] = st;
        ushort4 eA0 = sRI[w][c16];
        ushort4 eA1 = sRI[w][16 + c16];
        ushort4 eB0 = sRI[w][32 + c16];
        ushort4 eB1 = sRI[w][48 + c16];

        // ---- feature A-frags from fp16 global (MFMA A layout) ----
        f16x8 afA0 = ((const f16x8*)(feat16 + ((size_t)(bo + eA0.w)) * 32))[q];
        f16x8 afA1 = ((const f16x8*)(feat16 + ((size_t)(bo + eA1.w)) * 32))[q];
        f16x8 afB0 = ((const f16x8*)(feat16 + ((size_t)(bo + eB0.w)) * 32))[q];
        f16x8 afB1 = ((const f16x8*)(feat16 + ((size_t)(bo + eB1.w)) * 32))[q];

        // ---- pe A-frags: array-free, packed f16x2 math ----
        f16x8 apA10, apA20, apA11, apA21, apB10, apB20, apB11, apB21;
        PE_FRAGS(eA0, apA10, apA20);
        PE_FRAGS(eA1, apA11, apA21);
        PE_FRAGS(eB0, apB10, apB20);
        PE_FRAGS(eB1, apB11, apB21);

        // ---- per-N-tile: 3 shared B-frags, 12 MFMAs, reduce, global hm ----
#pragma unroll 2
        for (int nt = 0; nt < 8; ++nt) {
            f16x8 bf0 = B1f[nt * 64 + l];
            f16x8 bf1 = B1f[(8 + nt) * 64 + l];
            f16x8 bf2 = B1f[(16 + nt) * 64 + l];
            f32x4 aA0, aA1, aB0, aB1;
            aA0[0] = aA0[1] = aA0[2] = aA0[3] = bias1[nt];
            aA1 = aA0; aB0 = aA0; aB1 = aA0;
            aA0 = __builtin_amdgcn_mfma_f32_16x16x32_f16(afA0,  bf0, aA0, 0, 0, 0);
            aA1 = __builtin_amdgcn_mfma_f32_16x16x32_f16(afA1,  bf0, aA1, 0, 0, 0);
            aB0 = __builtin_amdgcn_mfma_f32_16x16x32_f16(afB0,  bf0, aB0, 0, 0, 0);
            aB1 = __builtin_amdgcn_mfma_f32_16x16x32_f16(afB1,  bf0, aB1, 0, 0, 0);
            aA0 = __builtin_amdgcn_mfma_f32_16x16x32_f16(apA10, bf1, aA0, 0, 0, 0);
            aA1 = __builtin_amdgcn_mfma_f32_16x16x32_f16(apA11, bf1, aA1, 0, 0, 0);
            aB0 = __builtin_amdgcn_mfma_f32_16x16x32_f16(apB10, bf1, aB0, 0, 0, 0);
            aB1 = __builtin_amdgcn_mfma_f32_16x16x32_f16(apB11, bf1, aB1, 0, 0, 0);
            aA0 = __builtin_amdgcn_mfma_f32_16x16x32_f16(apA20, bf2, aA0, 0, 0, 0);
            aA1 = __builtin_amdgcn_mfma_f32_16x16x32_f16(apA21, bf2, aA1, 0, 0, 0);
            aB0 = __builtin_amdgcn_mfma_f32_16x16x32_f16(apB20, bf2, aB0, 0, 0, 0);
            aB1 = __builtin_amdgcn_mfma_f32_16x16x32_f16(apB21, bf2, aB1, 0, 0, 0);

            float sA = fmaxf(aA0[0], 0.f) + fmaxf(aA0[1], 0.f)
                     + fmaxf(aA0[2], 0.f) + fmaxf(aA0[3], 0.f)
                     + fmaxf(aA1[0], 0.f) + fmaxf(aA1[1], 0.f)
                     + fmaxf(aA1[2], 0.f) + fmaxf(aA1[3], 0.f);
            float sB = fmaxf(aB0[0], 0.f) + fmaxf(aB0[1], 0.f)
                     + fmaxf(aB0[2], 0.f) + fmaxf(aB0[3], 0.f)
                     + fmaxf(aB1[0], 0.f) + fmaxf(aB1[1], 0.f)
                     + fmaxf(aB1[2], 0.f) + fmaxf(aB1[3], 0.f);
            sA += __shfl_xor(sA, 16, 64);
            sA += __shfl_xor(sA, 32, 64);
            sB += __shfl_xor(sB, 16, 64);
            sB += __shfl_xor(sB, 32, 64);
            if (q == 0) {
                hmG[(size_t)mA * HID + nt * 16 + c16]       = (_Float16)sA;
                hmG[(size_t)(mA + 1) * HID + nt * 16 + c16] = (_Float16)sB;
            }
        }
    }
}

// ---------------------------------------------------------------------------
// k2: OUT(16x64 per wave) = HM(16x128) @ W2s + b2 — the verified epilogue,
// now a standalone kernel reading hm from d_out (f16 overlay) and
// overwriting d_out with the f32 result IN PLACE.  Safe: each wave reads
// only its own 16 rows, and every store depends (via acc2) on all loads.
// grid 1024 x 256 thr (4 waves, 16 points/wave). No LDS -> full occupancy.
// ---------------------------------------------------------------------------
__global__ __launch_bounds__(256) void agg_epilogue(
    const _Float16* __restrict__ gW2,     // W2 frags (16 tiles, pre-scaled /32)
    const float* __restrict__ b2g,        // (64)
    float* __restrict__ out)              // in: hm f16 overlay; out: f32
{
    const int t = threadIdx.x;
    const int w = t >> 6, l = t & 63, q = (l >> 4), c16 = l & 15;
    const int wbase = blockIdx.x * 64 + w * 16;
    const _Float16* hmG = (const _Float16*)out;

    const f16x8* W2f = (const f16x8*)gW2;
    f32x4 acc2[4];
#pragma unroll
    for (int nt = 0; nt < 4; ++nt) {
        f32x4 z; float bv = b2g[nt * 16 + c16];
        z[0] = z[1] = z[2] = z[3] = bv;
        acc2[nt] = z;
    }
#pragma unroll
    for (int ks = 0; ks < 4; ++ks) {
        f16x8 a2 = *(const f16x8*)&hmG[(size_t)(wbase + c16) * HID + ks * 32 + q * 8];
#pragma unroll
        for (int nt = 0; nt < 4; ++nt) {
            f16x8 bf = W2f[(ks * 4 + nt) * 64 + l];
            acc2[nt] = __builtin_amdgcn_mfma_f32_16x16x32_f16(a2, bf, acc2[nt], 0, 0, 0);
        }
    }
#pragma unroll
    for (int nt = 0; nt < 4; ++nt)
#pragma unroll
        for (int r = 0; r < 4; ++r)
            out[(size_t)(wbase + q * 4 + r) * OUTF + nt * 16 + c16] = acc2[nt][r];
}

// ---------------------------------------------------------------------------
extern "C" void kernel_launch(void* const* d_in, const int* in_sizes, int n_in,
                              void* d_out, int out_size, void* d_ws, size_t ws_size,
                              hipStream_t stream)
{
    const float* points   = (const float*)d_in[0];
    const float* features = (const float*)d_in[1];
    // d_in[2] density: provably unused (softmax over K identical values = 1/K)
    const int*   nbr      = (const int*)d_in[3];
    const float* pe_w1    = (const float*)d_in[4];
    const float* pe_b1    = (const float*)d_in[5];
    const float* pe_w2    = (const float*)d_in[6];
    const float* pe_b2    = (const float*)d_in[7];
    const float* mlp_w1   = (const float*)d_in[8];
    const float* mlp_b1   = (const float*)d_in[9];
    const float* mlp_w2   = (const float*)d_in[10];
    const float* mlp_b2   = (const float*)d_in[11];

    float* wsf = (float*)d_ws;
    float*    b1c    = wsf;                         // 128 f32
    _Float16* gB1    = (_Float16*)(wsf + 128);      // 12288 f16
    _Float16* gW2    = (_Float16*)(wsf + 6272);     // 8192 f16
    float4*   pts4   = (float4*)(wsf + 10368);      // 65536 float4
    _Float16* feat16 = (_Float16*)(wsf + 272512);   // 2097152 f16
    // hm lives in d_out: 65536 x 128 f16 = 16,777,216 B == 65536 x 64 f32

    prep_all<<<2345, 256, 0, stream>>>(
        pe_w2, pe_b2, mlp_w1, mlp_b1, mlp_w2, features, points,
        gB1, gW2, b1c, feat16, pts4);

    DensityAwareFeatureAggregator_main<<<1024, 512, 0, stream>>>(
        pts4, feat16, nbr, pe_w1, pe_b1, b1c, gB1,
        (_Float16*)d_out);

    agg_epilogue<<<1024, 256, 0, stream>>>(
        gW2, mlp_b2, (float*)d_out);
}

// Round 9
// 177.780 us; speedup vs baseline: 1.7618x; 1.0036x over previous
//
#include <hip/hip_runtime.h>

#define BB   4
#define NN   16384
#define KK   32
#define HID  128
#define OUTF 64

typedef _Float16 f16x8 __attribute__((ext_vector_type(8)));
typedef _Float16 f16x4 __attribute__((ext_vector_type(4)));
typedef _Float16 f16x2 __attribute__((ext_vector_type(2)));
typedef float    f32x4 __attribute__((ext_vector_type(4)));
typedef float    f32x2 __attribute__((ext_vector_type(2)));

static __device__ __forceinline__ unsigned short h2u(_Float16 h) {
    union { _Float16 h; unsigned short u; } c; c.h = h; return c.u;
}
static __device__ __forceinline__ _Float16 u2h(unsigned short u) {
    union { _Float16 h; unsigned short u; } c; c.u = u; return c.h;
}

// packed relu on a float2 slice of an MFMA quad
#define RELU2(V, I0, I1)                                                    \
    __builtin_elementwise_max(__builtin_shufflevector((V), (V), I0, I1), z2)

// pe column-pair MAC: v = bias2 + t.xy*rx + t.zw*ry + t[4:5]*rz  (v_pk_fma_f16)
#define PE_HALF(T, RX, RY, RZ)                                              \
    (__builtin_shufflevector((T), (T), 6, 7)                                \
     + __builtin_shufflevector((T), (T), 0, 1) * (RX)                       \
     + __builtin_shufflevector((T), (T), 2, 3) * (RY)                       \
     + __builtin_shufflevector((T), (T), 4, 5) * (RZ))

// Array-free pe fragment builder: named temporaries only, relu via pk_max,
// f16x8 assembly via shufflevector (register placement, no insert chains).
#define PE_FRAGS(E, O1, O2)                                                 \
    do {                                                                    \
        _Float16 _hx = u2h((E).x), _hy = u2h((E).y), _hz = u2h((E).z);      \
        f16x2 _rx = { _hx, _hx }, _ry = { _hy, _hy }, _rz = { _hz, _hz };   \
        f16x2 _z = { (_Float16)0.f, (_Float16)0.f };                        \
        f16x2 _a0 = __builtin_elementwise_max(PE_HALF(tab1[0], _rx, _ry, _rz), _z); \
        f16x2 _a1 = __builtin_elementwise_max(PE_HALF(tab1[1], _rx, _ry, _rz), _z); \
        f16x2 _a2 = __builtin_elementwise_max(PE_HALF(tab1[2], _rx, _ry, _rz), _z); \
        f16x2 _a3 = __builtin_elementwise_max(PE_HALF(tab1[3], _rx, _ry, _rz), _z); \
        f16x2 _b0 = __builtin_elementwise_max(PE_HALF(tab2[0], _rx, _ry, _rz), _z); \
        f16x2 _b1 = __builtin_elementwise_max(PE_HALF(tab2[1], _rx, _ry, _rz), _z); \
        f16x2 _b2 = __builtin_elementwise_max(PE_HALF(tab2[2], _rx, _ry, _rz), _z); \
        f16x2 _b3 = __builtin_elementwise_max(PE_HALF(tab2[3], _rx, _ry, _rz), _z); \
        f16x4 _al = __builtin_shufflevector(_a0, _a1, 0, 1, 2, 3);          \
        f16x4 _ah = __builtin_shufflevector(_a2, _a3, 0, 1, 2, 3);          \
        f16x4 _bl = __builtin_shufflevector(_b0, _b1, 0, 1, 2, 3);          \
        f16x4 _bh = __builtin_shufflevector(_b2, _b3, 0, 1, 2, 3);          \
        O1 = __builtin_shufflevector(_al, _ah, 0, 1, 2, 3, 4, 5, 6, 7);     \
        O2 = __builtin_shufflevector(_bl, _bh, 0, 1, 2, 3, 4, 5, 6, 7);     \
    } while (0)

// ---------------------------------------------------------------------------
// prep_all: R1 champion prep, unchanged.
// blocks 0..23   : gB1 tile pack (24 tiles, 16x16x32 B-layout)
// blocks 24..39  : gW2 tile pack (16 tiles), pre-scaled by 1/32 (mean fold)
// blocks 40..2343: feat fp32->fp16 + points->float4
// block  2344    : b1c = mlp_b1 + pe_b2 @ W1b
// ---------------------------------------------------------------------------
__global__ __launch_bounds__(256) void prep_all(
    const float* __restrict__ pe_w2, const float* __restrict__ pe_b2,
    const float* __restrict__ mlp_w1, const float* __restrict__ mlp_b1,
    const float* __restrict__ mlp_w2,
    const float* __restrict__ features, const float* __restrict__ points,
    _Float16* __restrict__ gB1, _Float16* __restrict__ gW2,
    float* __restrict__ b1c,
    _Float16* __restrict__ feat16, float4* __restrict__ pts4)
{
    const int bid = blockIdx.x, tid = threadIdx.x;
    if (bid >= 40) {
        if (bid == 2344) {
            if (tid < HID) {
                float a = mlp_b1[tid];
#pragma unroll 16
                for (int c = 0; c < 64; ++c)
                    a = fmaf(pe_b2[c], mlp_w1[(32 + c) * HID + tid], a);
                b1c[tid] = a;
            }
            return;
        }
        int t = (bid - 40) * 256 + tid;
        if (t < BB * NN * 8) {
            float4 v = ((const float4*)features)[t];
            f16x4 h;
            h[0] = (_Float16)v.x; h[1] = (_Float16)v.y;
            h[2] = (_Float16)v.z; h[3] = (_Float16)v.w;
            *(f16x4*)(feat16 + (size_t)t * 4) = h;
        } else {
            int i = t - BB * NN * 8;
            if (i < BB * NN) {
                const float* p = points + (size_t)i * 3;
                pts4[i] = make_float4(p[0], p[1], p[2], 0.f);
            }
        }
        return;
    }
    if (bid < 24) {   // gB1: tile (ks,nt); element e: l=e>>3, j=e&7
        int ks = bid >> 3, nt = bid & 7;
        for (int e = tid; e < 512; e += 256) {
            int l = e >> 3, j = e & 7;
            int k = ks * 32 + (l >> 4) * 8 + j;
            int n = nt * 16 + (l & 15);
            float v;
            if (k < 32) {
                v = mlp_w1[k * HID + n];
            } else {
                int r = k - 32;
                v = 0.f;
#pragma unroll 16
                for (int c = 0; c < 64; ++c)
                    v = fmaf(pe_w2[r * 64 + c], mlp_w1[(32 + c) * HID + n], v);
            }
            gB1[bid * 512 + e] = (_Float16)v;
        }
    } else {          // gW2 — pre-scaled by 1/32 so hm stores skip the mean mul
        int tb = bid - 24;
        int ks = tb >> 2, nt = tb & 3;
        for (int e = tid; e < 512; e += 256) {
            int l = e >> 3, j = e & 7;
            int k = ks * 32 + (l >> 4) * 8 + j;
            int n = nt * 16 + (l & 15);
            gW2[tb * 512 + e] = (_Float16)(mlp_w2[k * OUTF + n] * 0.03125f);
        }
    }
}

// ---------------------------------------------------------------------------
// Main: R1 champion structure EXACTLY (512 thr, 8 waves, fused epilogue —
// R8 proved occupancy is register-capped at ~16 waves/CU, so the LDS split
// bought nothing and cost a 2nd kernel; reverted).  Three in-place VALU
// cuts in the nt loop, no new live-through state (R2/R3/R4 spill lesson):
//  1. bias-as-C via ONE transient splat per nt shared by all 4 first-MFMAs
//     (4 movs instead of 16 per nt; exact same math).
//  2. packed float2 relu+add reduce (v_pk_add_f32; shorter serial chain;
//     f32 re-association only).
//  3. s_setprio(1) around the MFMA cluster (barrier-free drifted waves).
// ---------------------------------------------------------------------------
__global__ __launch_bounds__(512, 4) void DensityAwareFeatureAggregator_main(
    const float4* __restrict__ pts4,      // (B*N) padded, global index
    const _Float16* __restrict__ feat16,  // (B*N,32) f16
    const int*   __restrict__ nbr,        // (B,N,32)
    const float* __restrict__ pe_w1,      // (3,64)
    const float* __restrict__ pe_b1,      // (64)
    const float* __restrict__ b1c,        // (128) fused bias
    const _Float16* __restrict__ gB1,     // W1c frags (24 tiles)
    const _Float16* __restrict__ gW2,     // W2 frags (16 tiles, pre-scaled /32)
    const float* __restrict__ b2g,        // (64)
    float* __restrict__ out)              // (B,N,64)
{
    __shared__ __align__(16) _Float16 sB1[24 * 512];     // 24576 B
    __shared__ __align__(16) f16x8    sTabH[32];         //   512 B
    __shared__ __align__(16) ushort4  sRI[8][64];        //  4096 B
    __shared__ __align__(16) _Float16 sHM[8][16 * 136];  // 34816 B
    // total 64000 B -> 2 blocks/CU (reg-capped at 16 waves/CU anyway)

    const int t = threadIdx.x;
    {
        const uint4* g = (const uint4*)gB1;
        uint4* d = (uint4*)sB1;
        for (int i = t; i < 1536; i += 512) d[i] = g[i];
    }
    if (t < 32) {   // col-pair tables: {x0,x1,y0,y1,z0,z1,b0,b1}
        int cp = t;
        f16x8 e;
        e[0] = (_Float16)pe_w1[2 * cp];       e[1] = (_Float16)pe_w1[2 * cp + 1];
        e[2] = (_Float16)pe_w1[64 + 2 * cp];  e[3] = (_Float16)pe_w1[64 + 2 * cp + 1];
        e[4] = (_Float16)pe_w1[128 + 2 * cp]; e[5] = (_Float16)pe_w1[128 + 2 * cp + 1];
        e[6] = (_Float16)pe_b1[2 * cp];       e[7] = (_Float16)pe_b1[2 * cp + 1];
        sTabH[cp] = e;
    }
    __syncthreads();

    const int w = t >> 6, l = t & 63, q = l >> 4, c16 = l & 15;
    // 512 blocks: XCD-swizzled bijective mapping (bid&7 = XCD, 64 blocks each)
    const int nb   = (blockIdx.x & 7) * 64 + (blockIdx.x >> 3);
    const int base = (nb * 8 + w) * 16;
    const int bo   = base & ~(NN - 1);   // batch offset into flat point ids

    f16x8 tab1[4], tab2[4];
#pragma unroll
    for (int u = 0; u < 4; ++u) {
        tab1[u] = sTabH[q * 4 + u];
        tab2[u] = sTabH[16 + q * 4 + u];
    }
    float bias1[8];
#pragma unroll
    for (int nt = 0; nt < 8; ++nt) bias1[nt] = b1c[nt * 16 + c16];

    const f16x8* B1f = (const f16x8*)sB1;
    _Float16* hmw = &sHM[w][0];

#pragma unroll 1
    for (int p2 = 0; p2 < 8; ++p2) {
        const int mA = base + 2 * p2;
        // ---- full-wave staging: lanes 0-31 point A, 32-63 point B ----
        int idx = nbr[(size_t)mA * KK + l];
        float4 pc = pts4[mA + (l >> 5)];
        float4 pn = pts4[bo + idx];
        ushort4 st;
        st.x = h2u((_Float16)(pn.x - pc.x));
        st.y = h2u((_Float16)(pn.y - pc.y));
        st.z = h2u((_Float16)(pn.z - pc.z));
        st.w = (unsigned short)idx;
        sRI[w][l] = st;
        ushort4 eA0 = sRI[w][c16];
        ushort4 eA1 = sRI[w][16 + c16];
        ushort4 eB0 = sRI[w][32 + c16];
        ushort4 eB1 = sRI[w][48 + c16];

        // ---- feature A-frags from fp16 global (MFMA A layout) ----
        f16x8 afA0 = ((const f16x8*)(feat16 + ((size_t)(bo + eA0.w)) * 32))[q];
        f16x8 afA1 = ((const f16x8*)(feat16 + ((size_t)(bo + eA1.w)) * 32))[q];
        f16x8 afB0 = ((const f16x8*)(feat16 + ((size_t)(bo + eB0.w)) * 32))[q];
        f16x8 afB1 = ((const f16x8*)(feat16 + ((size_t)(bo + eB1.w)) * 32))[q];

        // ---- pe A-frags: array-free, packed f16x2 math ----
        f16x8 apA10, apA20, apA11, apA21, apB10, apB20, apB11, apB21;
        PE_FRAGS(eA0, apA10, apA20);
        PE_FRAGS(eA1, apA11, apA21);
        PE_FRAGS(eB0, apB10, apB20);
        PE_FRAGS(eB1, apB11, apB21);

        // ---- per-N-tile: 3 shared B-frags, 12 MFMAs, packed reduce ----
#pragma unroll 2
        for (int nt = 0; nt < 8; ++nt) {
            f16x8 bf0 = B1f[nt * 64 + l];
            f16x8 bf1 = B1f[(8 + nt) * 64 + l];
            f16x8 bf2 = B1f[(16 + nt) * 64 + l];
            // ONE transient bias splat, shared as C by all 4 first-MFMAs
            // (4 movs/nt instead of 16; dies within the iteration).
            f32x4 bsp;
            bsp[0] = bsp[1] = bsp[2] = bsp[3] = bias1[nt];
            __builtin_amdgcn_s_setprio(1);
            f32x4 aA0 = __builtin_amdgcn_mfma_f32_16x16x32_f16(afA0,  bf0, bsp, 0, 0, 0);
            f32x4 aA1 = __builtin_amdgcn_mfma_f32_16x16x32_f16(afA1,  bf0, bsp, 0, 0, 0);
            f32x4 aB0 = __builtin_amdgcn_mfma_f32_16x16x32_f16(afB0,  bf0, bsp, 0, 0, 0);
            f32x4 aB1 = __builtin_amdgcn_mfma_f32_16x16x32_f16(afB1,  bf0, bsp, 0, 0, 0);
            aA0 = __builtin_amdgcn_mfma_f32_16x16x32_f16(apA10, bf1, aA0, 0, 0, 0);
            aA1 = __builtin_amdgcn_mfma_f32_16x16x32_f16(apA11, bf1, aA1, 0, 0, 0);
            aB0 = __builtin_amdgcn_mfma_f32_16x16x32_f16(apB10, bf1, aB0, 0, 0, 0);
            aB1 = __builtin_amdgcn_mfma_f32_16x16x32_f16(apB11, bf1, aB1, 0, 0, 0);
            aA0 = __builtin_amdgcn_mfma_f32_16x16x32_f16(apA20, bf2, aA0, 0, 0, 0);
            aA1 = __builtin_amdgcn_mfma_f32_16x16x32_f16(apA21, bf2, aA1, 0, 0, 0);
            aB0 = __builtin_amdgcn_mfma_f32_16x16x32_f16(apB20, bf2, aB0, 0, 0, 0);
            aB1 = __builtin_amdgcn_mfma_f32_16x16x32_f16(apB21, bf2, aB1, 0, 0, 0);
            __builtin_amdgcn_s_setprio(0);

            // packed float2 relu + add (v_pk_add_f32; shallower chain)
            f32x2 z2 = { 0.f, 0.f };
            f32x2 rA = (RELU2(aA0, 0, 1) + RELU2(aA0, 2, 3))
                     + (RELU2(aA1, 0, 1) + RELU2(aA1, 2, 3));
            f32x2 rB = (RELU2(aB0, 0, 1) + RELU2(aB0, 2, 3))
                     + (RELU2(aB1, 0, 1) + RELU2(aB1, 2, 3));
            float sA = rA[0] + rA[1];
            float sB = rB[0] + rB[1];
            sA += __shfl_xor(sA, 16, 64);
            sA += __shfl_xor(sA, 32, 64);
            sB += __shfl_xor(sB, 16, 64);
            sB += __shfl_xor(sB, 32, 64);
            if (q == 0) {
                hmw[(2 * p2) * 136 + nt * 16 + c16]     = (_Float16)sA;
                hmw[(2 * p2 + 1) * 136 + nt * 16 + c16] = (_Float16)sB;
            }
        }
    }

    // ---- epilogue: OUT(16x64) = HM(16x128) @ W2s + b2 (verified R2-R7) ----
    const f16x8* W2f = (const f16x8*)gW2;
    f32x4 acc2[4];
#pragma unroll
    for (int nt = 0; nt < 4; ++nt) {
        f32x4 z; float bv = b2g[nt * 16 + c16];
        z[0] = z[1] = z[2] = z[3] = bv;
        acc2[nt] = z;
    }
#pragma unroll
    for (int ks = 0; ks < 4; ++ks) {
        f16x8 a2 = *(const f16x8*)&hmw[c16 * 136 + ks * 32 + q * 8];
#pragma unroll
        for (int nt = 0; nt < 4; ++nt) {
            f16x8 bf = W2f[(ks * 4 + nt) * 64 + l];
            acc2[nt] = __builtin_amdgcn_mfma_f32_16x16x32_f16(a2, bf, acc2[nt], 0, 0, 0);
        }
    }
#pragma unroll
    for (int nt = 0; nt < 4; ++nt)
#pragma unroll
        for (int r = 0; r < 4; ++r)
            out[(size_t)(base + q * 4 + r) * OUTF + nt * 16 + c16] = acc2[nt][r];
}

// ---------------------------------------------------------------------------
extern "C" void kernel_launch(void* const* d_in, const int* in_sizes, int n_in,
                              void* d_out, int out_size, void* d_ws, size_t ws_size,
                              hipStream_t stream)
{
    const float* points   = (const float*)d_in[0];
    const float* features = (const float*)d_in[1];
    // d_in[2] density: provably unused (softmax over K identical values = 1/K)
    const int*   nbr      = (const int*)d_in[3];
    const float* pe_w1    = (const float*)d_in[4];
    const float* pe_b1    = (const float*)d_in[5];
    const float* pe_w2    = (const float*)d_in[6];
    const float* pe_b2    = (const float*)d_in[7];
    const float* mlp_w1   = (const float*)d_in[8];
    const float* mlp_b1   = (const float*)d_in[9];
    const float* mlp_w2   = (const float*)d_in[10];
    const float* mlp_b2   = (const float*)d_in[11];

    float* wsf = (float*)d_ws;
    float*    b1c    = wsf;                         // 128 f32
    _Float16* gB1    = (_Float16*)(wsf + 128);      // 12288 f16
    _Float16* gW2    = (_Float16*)(wsf + 6272);     // 8192 f16
    float4*   pts4   = (float4*)(wsf + 10368);      // 65536 float4
    _Float16* feat16 = (_Float16*)(wsf + 272512);   // 2097152 f16

    prep_all<<<2345, 256, 0, stream>>>(
        pe_w2, pe_b2, mlp_w1, mlp_b1, mlp_w2, features, points,
        gB1, gW2, b1c, feat16, pts4);

    DensityAwareFeatureAggregator_main<<<512, 512, 0, stream>>>(
        pts4, feat16, nbr, pe_w1, pe_b1, b1c, gB1, gW2, mlp_b2,
        (float*)d_out);
}

// Round 10
// 172.555 us; speedup vs baseline: 1.8151x; 1.0303x over previous
//
#include <hip/hip_runtime.h>

#define BB   4
#define NN   16384
#define KK   32
#define HID  128
#define OUTF 64

typedef _Float16 f16x8 __attribute__((ext_vector_type(8)));
typedef _Float16 f16x4 __attribute__((ext_vector_type(4)));
typedef _Float16 f16x2 __attribute__((ext_vector_type(2)));
typedef float    f32x4 __attribute__((ext_vector_type(4)));

static __device__ __forceinline__ unsigned short h2u(_Float16 h) {
    union { _Float16 h; unsigned short u; } c; c.h = h; return c.u;
}
static __device__ __forceinline__ _Float16 u2h(unsigned short u) {
    union { _Float16 h; unsigned short u; } c; c.u = u; return c.h;
}

// pe column-pair MAC: v = bias2 + t.xy*rx + t.zw*ry + t[4:5]*rz  (v_pk_fma_f16)
#define PE_HALF(T, RX, RY, RZ)                                              \
    (__builtin_shufflevector((T), (T), 6, 7)                                \
     + __builtin_shufflevector((T), (T), 0, 1) * (RX)                       \
     + __builtin_shufflevector((T), (T), 2, 3) * (RY)                       \
     + __builtin_shufflevector((T), (T), 4, 5) * (RZ))

// Array-free pe fragment builder: named temporaries only, relu via pk_max,
// f16x8 assembly via shufflevector (register placement, no insert chains).
#define PE_FRAGS(E, O1, O2)                                                 \
    do {                                                                    \
        _Float16 _hx = u2h((E).x), _hy = u2h((E).y), _hz = u2h((E).z);      \
        f16x2 _rx = { _hx, _hx }, _ry = { _hy, _hy }, _rz = { _hz, _hz };   \
        f16x2 _z = { (_Float16)0.f, (_Float16)0.f };                        \
        f16x2 _a0 = __builtin_elementwise_max(PE_HALF(tab1[0], _rx, _ry, _rz), _z); \
        f16x2 _a1 = __builtin_elementwise_max(PE_HALF(tab1[1], _rx, _ry, _rz), _z); \
        f16x2 _a2 = __builtin_elementwise_max(PE_HALF(tab1[2], _rx, _ry, _rz), _z); \
        f16x2 _a3 = __builtin_elementwise_max(PE_HALF(tab1[3], _rx, _ry, _rz), _z); \
        f16x2 _b0 = __builtin_elementwise_max(PE_HALF(tab2[0], _rx, _ry, _rz), _z); \
        f16x2 _b1 = __builtin_elementwise_max(PE_HALF(tab2[1], _rx, _ry, _rz), _z); \
        f16x2 _b2 = __builtin_elementwise_max(PE_HALF(tab2[2], _rx, _ry, _rz), _z); \
        f16x2 _b3 = __builtin_elementwise_max(PE_HALF(tab2[3], _rx, _ry, _rz), _z); \
        f16x4 _al = __builtin_shufflevector(_a0, _a1, 0, 1, 2, 3);          \
        f16x4 _ah = __builtin_shufflevector(_a2, _a3, 0, 1, 2, 3);          \
        f16x4 _bl = __builtin_shufflevector(_b0, _b1, 0, 1, 2, 3);          \
        f16x4 _bh = __builtin_shufflevector(_b2, _b3, 0, 1, 2, 3);          \
        O1 = __builtin_shufflevector(_al, _ah, 0, 1, 2, 3, 4, 5, 6, 7);     \
        O2 = __builtin_shufflevector(_bl, _bh, 0, 1, 2, 3, 4, 5, 6, 7);     \
    } while (0)

// ---------------------------------------------------------------------------
// prep_all: R1 champion prep, unchanged.
// blocks 0..23   : gB1 tile pack (24 tiles, 16x16x32 B-layout)
// blocks 24..39  : gW2 tile pack (16 tiles), pre-scaled by 1/32 (mean fold)
// blocks 40..2343: feat fp32->fp16 + points->float4
// block  2344    : b1c = mlp_b1 + pe_b2 @ W1b
// ---------------------------------------------------------------------------
__global__ __launch_bounds__(256) void prep_all(
    const float* __restrict__ pe_w2, const float* __restrict__ pe_b2,
    const float* __restrict__ mlp_w1, const float* __restrict__ mlp_b1,
    const float* __restrict__ mlp_w2,
    const float* __restrict__ features, const float* __restrict__ points,
    _Float16* __restrict__ gB1, _Float16* __restrict__ gW2,
    float* __restrict__ b1c,
    _Float16* __restrict__ feat16, float4* __restrict__ pts4)
{
    const int bid = blockIdx.x, tid = threadIdx.x;
    if (bid >= 40) {
        if (bid == 2344) {
            if (tid < HID) {
                float a = mlp_b1[tid];
#pragma unroll 16
                for (int c = 0; c < 64; ++c)
                    a = fmaf(pe_b2[c], mlp_w1[(32 + c) * HID + tid], a);
                b1c[tid] = a;
            }
            return;
        }
        int t = (bid - 40) * 256 + tid;
        if (t < BB * NN * 8) {
            float4 v = ((const float4*)features)[t];
            f16x4 h;
            h[0] = (_Float16)v.x; h[1] = (_Float16)v.y;
            h[2] = (_Float16)v.z; h[3] = (_Float16)v.w;
            *(f16x4*)(feat16 + (size_t)t * 4) = h;
        } else {
            int i = t - BB * NN * 8;
            if (i < BB * NN) {
                const float* p = points + (size_t)i * 3;
                pts4[i] = make_float4(p[0], p[1], p[2], 0.f);
            }
        }
        return;
    }
    if (bid < 24) {   // gB1: tile (ks,nt); element e: l=e>>3, j=e&7
        int ks = bid >> 3, nt = bid & 7;
        for (int e = tid; e < 512; e += 256) {
            int l = e >> 3, j = e & 7;
            int k = ks * 32 + (l >> 4) * 8 + j;
            int n = nt * 16 + (l & 15);
            float v;
            if (k < 32) {
                v = mlp_w1[k * HID + n];
            } else {
                int r = k - 32;
                v = 0.f;
#pragma unroll 16
                for (int c = 0; c < 64; ++c)
                    v = fmaf(pe_w2[r * 64 + c], mlp_w1[(32 + c) * HID + n], v);
            }
            gB1[bid * 512 + e] = (_Float16)v;
        }
    } else {          // gW2 — pre-scaled by 1/32 so hm stores skip the mean mul
        int tb = bid - 24;
        int ks = tb >> 2, nt = tb & 3;
        for (int e = tid; e < 512; e += 256) {
            int l = e >> 3, j = e & 7;
            int k = ks * 32 + (l >> 4) * 8 + j;
            int n = nt * 16 + (l & 15);
            gW2[tb * 512 + e] = (_Float16)(mlp_w2[k * OUTF + n] * 0.03125f);
        }
    }
}

// ---------------------------------------------------------------------------
// Main: R1 champion structure EXACTLY, with ONE isolated change (R9 ablation:
// its three changes combined cut VALUBusy 58->51 but spilled ~9MB; this keeps
// only the change that SHRINKS live state):
//   bias-as-C: ONE transient splat quad per nt iteration, shared as the C
//   operand by all 4 first-MFMAs (4 movs/nt instead of 16). Scalar fmaxf
//   reduce and no setprio — both reverted to R1 form.
// ---------------------------------------------------------------------------
__global__ __launch_bounds__(512, 4) void DensityAwareFeatureAggregator_main(
    const float4* __restrict__ pts4,      // (B*N) padded, global index
    const _Float16* __restrict__ feat16,  // (B*N,32) f16
    const int*   __restrict__ nbr,        // (B,N,32)
    const float* __restrict__ pe_w1,      // (3,64)
    const float* __restrict__ pe_b1,      // (64)
    const float* __restrict__ b1c,        // (128) fused bias
    const _Float16* __restrict__ gB1,     // W1c frags (24 tiles)
    const _Float16* __restrict__ gW2,     // W2 frags (16 tiles, pre-scaled /32)
    const float* __restrict__ b2g,        // (64)
    float* __restrict__ out)              // (B,N,64)
{
    __shared__ __align__(16) _Float16 sB1[24 * 512];     // 24576 B
    __shared__ __align__(16) f16x8    sTabH[32];         //   512 B
    __shared__ __align__(16) ushort4  sRI[8][64];        //  4096 B
    __shared__ __align__(16) _Float16 sHM[8][16 * 136];  // 34816 B
    // total 64000 B -> 2 blocks/CU, 16 waves/CU

    const int t = threadIdx.x;
    {
        const uint4* g = (const uint4*)gB1;
        uint4* d = (uint4*)sB1;
        for (int i = t; i < 1536; i += 512) d[i] = g[i];
    }
    if (t < 32) {   // col-pair tables: {x0,x1,y0,y1,z0,z1,b0,b1}
        int cp = t;
        f16x8 e;
        e[0] = (_Float16)pe_w1[2 * cp];       e[1] = (_Float16)pe_w1[2 * cp + 1];
        e[2] = (_Float16)pe_w1[64 + 2 * cp];  e[3] = (_Float16)pe_w1[64 + 2 * cp + 1];
        e[4] = (_Float16)pe_w1[128 + 2 * cp]; e[5] = (_Float16)pe_w1[128 + 2 * cp + 1];
        e[6] = (_Float16)pe_b1[2 * cp];       e[7] = (_Float16)pe_b1[2 * cp + 1];
        sTabH[cp] = e;
    }
    __syncthreads();

    const int w = t >> 6, l = t & 63, q = l >> 4, c16 = l & 15;
    // 512 blocks: XCD-swizzled bijective mapping (bid&7 = XCD, 64 blocks each)
    const int nb   = (blockIdx.x & 7) * 64 + (blockIdx.x >> 3);
    const int base = (nb * 8 + w) * 16;
    const int bo   = base & ~(NN - 1);   // batch offset into flat point ids

    f16x8 tab1[4], tab2[4];
#pragma unroll
    for (int u = 0; u < 4; ++u) {
        tab1[u] = sTabH[q * 4 + u];
        tab2[u] = sTabH[16 + q * 4 + u];
    }
    float bias1[8];
#pragma unroll
    for (int nt = 0; nt < 8; ++nt) bias1[nt] = b1c[nt * 16 + c16];

    const f16x8* B1f = (const f16x8*)sB1;
    _Float16* hmw = &sHM[w][0];

#pragma unroll 1
    for (int p2 = 0; p2 < 8; ++p2) {
        const int mA = base + 2 * p2;
        // ---- full-wave staging: lanes 0-31 point A, 32-63 point B ----
        int idx = nbr[(size_t)mA * KK + l];
        float4 pc = pts4[mA + (l >> 5)];
        float4 pn = pts4[bo + idx];
        ushort4 st;
        st.x = h2u((_Float16)(pn.x - pc.x));
        st.y = h2u((_Float16)(pn.y - pc.y));
        st.z = h2u((_Float16)(pn.z - pc.z));
        st.w = (unsigned short)idx;
        sRI[w][l] = st;
        ushort4 eA0 = sRI[w][c16];
        ushort4 eA1 = sRI[w][16 + c16];
        ushort4 eB0 = sRI[w][32 + c16];
        ushort4 eB1 = sRI[w][48 + c16];

        // ---- feature A-frags from fp16 global (MFMA A layout) ----
        f16x8 afA0 = ((const f16x8*)(feat16 + ((size_t)(bo + eA0.w)) * 32))[q];
        f16x8 afA1 = ((const f16x8*)(feat16 + ((size_t)(bo + eA1.w)) * 32))[q];
        f16x8 afB0 = ((const f16x8*)(feat16 + ((size_t)(bo + eB0.w)) * 32))[q];
        f16x8 afB1 = ((const f16x8*)(feat16 + ((size_t)(bo + eB1.w)) * 32))[q];

        // ---- pe A-frags: array-free, packed f16x2 math ----
        f16x8 apA10, apA20, apA11, apA21, apB10, apB20, apB11, apB21;
        PE_FRAGS(eA0, apA10, apA20);
        PE_FRAGS(eA1, apA11, apA21);
        PE_FRAGS(eB0, apB10, apB20);
        PE_FRAGS(eB1, apB11, apB21);

        // ---- per-N-tile: 3 shared B-frags, 12 MFMAs, reduce ----
#pragma unroll 2
        for (int nt = 0; nt < 8; ++nt) {
            f16x8 bf0 = B1f[nt * 64 + l];
            f16x8 bf1 = B1f[(8 + nt) * 64 + l];
            f16x8 bf2 = B1f[(16 + nt) * 64 + l];
            // ONE transient bias splat shared as C by the 4 first-MFMAs
            // (4 movs/nt instead of 16; dies within the iteration).
            f32x4 bsp;
            bsp[0] = bsp[1] = bsp[2] = bsp[3] = bias1[nt];
            f32x4 aA0 = __builtin_amdgcn_mfma_f32_16x16x32_f16(afA0,  bf0, bsp, 0, 0, 0);
            f32x4 aA1 = __builtin_amdgcn_mfma_f32_16x16x32_f16(afA1,  bf0, bsp, 0, 0, 0);
            f32x4 aB0 = __builtin_amdgcn_mfma_f32_16x16x32_f16(afB0,  bf0, bsp, 0, 0, 0);
            f32x4 aB1 = __builtin_amdgcn_mfma_f32_16x16x32_f16(afB1,  bf0, bsp, 0, 0, 0);
            aA0 = __builtin_amdgcn_mfma_f32_16x16x32_f16(apA10, bf1, aA0, 0, 0, 0);
            aA1 = __builtin_amdgcn_mfma_f32_16x16x32_f16(apA11, bf1, aA1, 0, 0, 0);
            aB0 = __builtin_amdgcn_mfma_f32_16x16x32_f16(apB10, bf1, aB0, 0, 0, 0);
            aB1 = __builtin_amdgcn_mfma_f32_16x16x32_f16(apB11, bf1, aB1, 0, 0, 0);
            aA0 = __builtin_amdgcn_mfma_f32_16x16x32_f16(apA20, bf2, aA0, 0, 0, 0);
            aA1 = __builtin_amdgcn_mfma_f32_16x16x32_f16(apA21, bf2, aA1, 0, 0, 0);
            aB0 = __builtin_amdgcn_mfma_f32_16x16x32_f16(apB20, bf2, aB0, 0, 0, 0);
            aB1 = __builtin_amdgcn_mfma_f32_16x16x32_f16(apB21, bf2, aB1, 0, 0, 0);

            float sA = fmaxf(aA0[0], 0.f) + fmaxf(aA0[1], 0.f)
                     + fmaxf(aA0[2], 0.f) + fmaxf(aA0[3], 0.f)
                     + fmaxf(aA1[0], 0.f) + fmaxf(aA1[1], 0.f)
                     + fmaxf(aA1[2], 0.f) + fmaxf(aA1[3], 0.f);
            float sB = fmaxf(aB0[0], 0.f) + fmaxf(aB0[1], 0.f)
                     + fmaxf(aB0[2], 0.f) + fmaxf(aB0[3], 0.f)
                     + fmaxf(aB1[0], 0.f) + fmaxf(aB1[1], 0.f)
                     + fmaxf(aB1[2], 0.f) + fmaxf(aB1[3], 0.f);
            sA += __shfl_xor(sA, 16, 64);
            sA += __shfl_xor(sA, 32, 64);
            sB += __shfl_xor(sB, 16, 64);
            sB += __shfl_xor(sB, 32, 64);
            if (q == 0) {
                hmw[(2 * p2) * 136 + nt * 16 + c16]     = (_Float16)sA;
                hmw[(2 * p2 + 1) * 136 + nt * 16 + c16] = (_Float16)sB;
            }
        }
    }

    // ---- epilogue: OUT(16x64) = HM(16x128) @ W2s + b2 (verified R2-R7) ----
    const f16x8* W2f = (const f16x8*)gW2;
    f32x4 acc2[4];
#pragma unroll
    for (int nt = 0; nt < 4; ++nt) {
        f32x4 z; float bv = b2g[nt * 16 + c16];
        z[0] = z[1] = z[2] = z[3] = bv;
        acc2[nt] = z;
    }
#pragma unroll
    for (int ks = 0; ks < 4; ++ks) {
        f16x8 a2 = *(const f16x8*)&hmw[c16 * 136 + ks * 32 + q * 8];
#pragma unroll
        for (int nt = 0; nt < 4; ++nt) {
            f16x8 bf = W2f[(ks * 4 + nt) * 64 + l];
            acc2[nt] = __builtin_amdgcn_mfma_f32_16x16x32_f16(a2, bf, acc2[nt], 0, 0, 0);
        }
    }
#pragma unroll
    for (int nt = 0; nt < 4; ++nt)
#pragma unroll
        for (int r = 0; r < 4; ++r)
            out[(size_t)(base + q * 4 + r) * OUTF + nt * 16 + c16] = acc2[nt][r];
}

// ---------------------------------------------------------------------------
extern "C" void kernel_launch(void* const* d_in, const int* in_sizes, int n_in,
                              void* d_out, int out_size, void* d_ws, size_t ws_size,
                              hipStream_t stream)
{
    const float* points   = (const float*)d_in[0];
    const float* features = (const float*)d_in[1];
    // d_in[2] density: provably unused (softmax over K identical values = 1/K)
    const int*   nbr      = (const int*)d_in[3];
    const float* pe_w1    = (const float*)d_in[4];
    const float* pe_b1    = (const float*)d_in[5];
    const float* pe_w2    = (const float*)d_in[6];
    const float* pe_b2    = (const float*)d_in[7];
    const float* mlp_w1   = (const float*)d_in[8];
    const float* mlp_b1   = (const float*)d_in[9];
    const float* mlp_w2   = (const float*)d_in[10];
    const float* mlp_b2   = (const float*)d_in[11];

    float* wsf = (float*)d_ws;
    float*    b1c    = wsf;                         // 128 f32
    _Float16* gB1    = (_Float16*)(wsf + 128);      // 12288 f16
    _Float16* gW2    = (_Float16*)(wsf + 6272);     // 8192 f16
    float4*   pts4   = (float4*)(wsf + 10368);      // 65536 float4
    _Float16* feat16 = (_Float16*)(wsf + 272512);   // 2097152 f16

    prep_all<<<2345, 256, 0, stream>>>(
        pe_w2, pe_b2, mlp_w1, mlp_b1, mlp_w2, features, points,
        gB1, gW2, b1c, feat16, pts4);

    DensityAwareFeatureAggregator_main<<<512, 512, 0, stream>>>(
        pts4, feat16, nbr, pe_w1, pe_b1, b1c, gB1, gW2, mlp_b2,
        (float*)d_out);
}

// Round 11
// 172.462 us; speedup vs baseline: 1.8161x; 1.0005x over previous
//
#include <hip/hip_runtime.h>

#define BB   4
#define NN   16384
#define KK   32
#define HID  128
#define OUTF 64

typedef _Float16 f16x8 __attribute__((ext_vector_type(8)));
typedef _Float16 f16x4 __attribute__((ext_vector_type(4)));
typedef _Float16 f16x2 __attribute__((ext_vector_type(2)));
typedef float    f32x4 __attribute__((ext_vector_type(4)));

static __device__ __forceinline__ unsigned short h2u(_Float16 h) {
    union { _Float16 h; unsigned short u; } c; c.h = h; return c.u;
}
static __device__ __forceinline__ _Float16 u2h(unsigned short u) {
    union { _Float16 h; unsigned short u; } c; c.u = u; return c.h;
}

// pe column-pair MAC: v = bias2 + t.xy*rx + t.zw*ry + t[4:5]*rz  (v_pk_fma_f16)
#define PE_HALF(T, RX, RY, RZ)                                              \
    (__builtin_shufflevector((T), (T), 6, 7)                                \
     + __builtin_shufflevector((T), (T), 0, 1) * (RX)                       \
     + __builtin_shufflevector((T), (T), 2, 3) * (RY)                       \
     + __builtin_shufflevector((T), (T), 4, 5) * (RZ))

// Array-free pe fragment builder: named temporaries only, relu via pk_max,
// f16x8 assembly via shufflevector (register placement, no insert chains).
#define PE_FRAGS(E, O1, O2)                                                 \
    do {                                                                    \
        _Float16 _hx = u2h((E).x), _hy = u2h((E).y), _hz = u2h((E).z);      \
        f16x2 _rx = { _hx, _hx }, _ry = { _hy, _hy }, _rz = { _hz, _hz };   \
        f16x2 _z = { (_Float16)0.f, (_Float16)0.f };                        \
        f16x2 _a0 = __builtin_elementwise_max(PE_HALF(tab1[0], _rx, _ry, _rz), _z); \
        f16x2 _a1 = __builtin_elementwise_max(PE_HALF(tab1[1], _rx, _ry, _rz), _z); \
        f16x2 _a2 = __builtin_elementwise_max(PE_HALF(tab1[2], _rx, _ry, _rz), _z); \
        f16x2 _a3 = __builtin_elementwise_max(PE_HALF(tab1[3], _rx, _ry, _rz), _z); \
        f16x2 _b0 = __builtin_elementwise_max(PE_HALF(tab2[0], _rx, _ry, _rz), _z); \
        f16x2 _b1 = __builtin_elementwise_max(PE_HALF(tab2[1], _rx, _ry, _rz), _z); \
        f16x2 _b2 = __builtin_elementwise_max(PE_HALF(tab2[2], _rx, _ry, _rz), _z); \
        f16x2 _b3 = __builtin_elementwise_max(PE_HALF(tab2[3], _rx, _ry, _rz), _z); \
        f16x4 _al = __builtin_shufflevector(_a0, _a1, 0, 1, 2, 3);          \
        f16x4 _ah = __builtin_shufflevector(_a2, _a3, 0, 1, 2, 3);          \
        f16x4 _bl = __builtin_shufflevector(_b0, _b1, 0, 1, 2, 3);          \
        f16x4 _bh = __builtin_shufflevector(_b2, _b3, 0, 1, 2, 3);          \
        O1 = __builtin_shufflevector(_al, _ah, 0, 1, 2, 3, 4, 5, 6, 7);     \
        O2 = __builtin_shufflevector(_bl, _bh, 0, 1, 2, 3, 4, 5, 6, 7);     \
    } while (0)

// ---------------------------------------------------------------------------
// prep_all: ONE kernel, no inter-block deps.
// blocks 0..23   : gB1 tile pack (24 tiles, 16x16x32 B-layout)
// blocks 24..39  : gW2 tile pack (16 tiles), pre-scaled by 1/32 (mean fold)
// blocks 40..2343: feat fp32->fp16 + points->float4
// block  2344    : b1c = mlp_b1 + pe_b2 @ W1b
// ---------------------------------------------------------------------------
__global__ __launch_bounds__(256) void prep_all(
    const float* __restrict__ pe_w2, const float* __restrict__ pe_b2,
    const float* __restrict__ mlp_w1, const float* __restrict__ mlp_b1,
    const float* __restrict__ mlp_w2,
    const float* __restrict__ features, const float* __restrict__ points,
    _Float16* __restrict__ gB1, _Float16* __restrict__ gW2,
    float* __restrict__ b1c,
    _Float16* __restrict__ feat16, float4* __restrict__ pts4)
{
    const int bid = blockIdx.x, tid = threadIdx.x;
    if (bid >= 40) {
        if (bid == 2344) {
            if (tid < HID) {
                float a = mlp_b1[tid];
#pragma unroll 16
                for (int c = 0; c < 64; ++c)
                    a = fmaf(pe_b2[c], mlp_w1[(32 + c) * HID + tid], a);
                b1c[tid] = a;
            }
            return;
        }
        int t = (bid - 40) * 256 + tid;
        if (t < BB * NN * 8) {
            float4 v = ((const float4*)features)[t];
            f16x4 h;
            h[0] = (_Float16)v.x; h[1] = (_Float16)v.y;
            h[2] = (_Float16)v.z; h[3] = (_Float16)v.w;
            *(f16x4*)(feat16 + (size_t)t * 4) = h;
        } else {
            int i = t - BB * NN * 8;
            if (i < BB * NN) {
                const float* p = points + (size_t)i * 3;
                pts4[i] = make_float4(p[0], p[1], p[2], 0.f);
            }
        }
        return;
    }
    if (bid < 24) {   // gB1: tile (ks,nt); element e: l=e>>3, j=e&7
        int ks = bid >> 3, nt = bid & 7;
        for (int e = tid; e < 512; e += 256) {
            int l = e >> 3, j = e & 7;
            int k = ks * 32 + (l >> 4) * 8 + j;
            int n = nt * 16 + (l & 15);
            float v;
            if (k < 32) {
                v = mlp_w1[k * HID + n];
            } else {
                int r = k - 32;
                v = 0.f;
#pragma unroll 16
                for (int c = 0; c < 64; ++c)
                    v = fmaf(pe_w2[r * 64 + c], mlp_w1[(32 + c) * HID + n], v);
            }
            gB1[bid * 512 + e] = (_Float16)v;
        }
    } else {          // gW2 — pre-scaled by 1/32 so hm stores skip the mean mul
        int tb = bid - 24;
        int ks = tb >> 2, nt = tb & 3;
        for (int e = tid; e < 512; e += 256) {
            int l = e >> 3, j = e & 7;
            int k = ks * 32 + (l >> 4) * 8 + j;
            int n = nt * 16 + (l & 15);
            gW2[tb * 512 + e] = (_Float16)(mlp_w2[k * OUTF + n] * 0.03125f);
        }
    }
}

// ---------------------------------------------------------------------------
// Main: R1 champion EXACTLY — the locked session best (main 73.5 us, WRITE
// 16.4 MB, zero spill).  Session structural-limit summary:
//  - MFMA floor ~25 us (51.5 GFLOP @ 2075 TF 16x16x32-f16 ceiling);
//    measured MFMA-busy ~22-25 us (MfmaUtil ~30%).
//  - Limiter: VALU issue ~42 us (58%) — ~3x algorithmic minimum from
//    packed-f16 codegen; VALU+MFMA combined issue ~87%.
//  - Unified 128-reg/wave budget at 4 waves/SIMD is exactly full
//    (VGPR 64 + accumulators): ALL added live state spills to scratch
//    (R2/R3/R4/R9/R10: WRITE_SIZE inflation at 1-150 MB scale).
//  - Occupancy register-capped at 16 waves/CU (R8: freeing 35 KB LDS
//    changed nothing); staging latency not on critical path (R6 null);
//    not memory-bound (4% HBM); bank conflicts negligible.
//  - Next step would be a ground-up 32x32x16-MFMA decomposition (+15%
//    pipe rate, -50% MFMA instr count), but its register budget does not
//    close with the 32-VGPR pe-table scheme without an LDS pe-exchange
//    that exceeds the LDS budget — a different kernel family.
// ---------------------------------------------------------------------------
__global__ __launch_bounds__(512, 4) void DensityAwareFeatureAggregator_main(
    const float4* __restrict__ pts4,      // (B*N) padded, global index
    const _Float16* __restrict__ feat16,  // (B*N,32) f16
    const int*   __restrict__ nbr,        // (B,N,32)
    const float* __restrict__ pe_w1,      // (3,64)
    const float* __restrict__ pe_b1,      // (64)
    const float* __restrict__ b1c,        // (128) fused bias
    const _Float16* __restrict__ gB1,     // W1c frags (24 tiles)
    const _Float16* __restrict__ gW2,     // W2 frags (16 tiles, pre-scaled /32)
    const float* __restrict__ b2g,        // (64)
    float* __restrict__ out)              // (B,N,64)
{
    __shared__ __align__(16) _Float16 sB1[24 * 512];     // 24576 B
    __shared__ __align__(16) f16x8    sTabH[32];         //   512 B
    __shared__ __align__(16) ushort4  sRI[8][64];        //  4096 B
    __shared__ __align__(16) _Float16 sHM[8][16 * 136];  // 34816 B
    // total 64000 B -> 2 blocks/CU, 16 waves/CU

    const int t = threadIdx.x;
    {
        const uint4* g = (const uint4*)gB1;
        uint4* d = (uint4*)sB1;
        for (int i = t; i < 1536; i += 512) d[i] = g[i];
    }
    if (t < 32) {   // col-pair tables: {x0,x1,y0,y1,z0,z1,b0,b1}
        int cp = t;
        f16x8 e;
        e[0] = (_Float16)pe_w1[2 * cp];       e[1] = (_Float16)pe_w1[2 * cp + 1];
        e[2] = (_Float16)pe_w1[64 + 2 * cp];  e[3] = (_Float16)pe_w1[64 + 2 * cp + 1];
        e[4] = (_Float16)pe_w1[128 + 2 * cp]; e[5] = (_Float16)pe_w1[128 + 2 * cp + 1];
        e[6] = (_Float16)pe_b1[2 * cp];       e[7] = (_Float16)pe_b1[2 * cp + 1];
        sTabH[cp] = e;
    }
    __syncthreads();

    const int w = t >> 6, l = t & 63, q = l >> 4, c16 = l & 15;
    // 512 blocks: XCD-swizzled bijective mapping (bid&7 = XCD, 64 blocks each)
    const int nb   = (blockIdx.x & 7) * 64 + (blockIdx.x >> 3);
    const int base = (nb * 8 + w) * 16;
    const int bo   = base & ~(NN - 1);   // batch offset into flat point ids

    f16x8 tab1[4], tab2[4];
#pragma unroll
    for (int u = 0; u < 4; ++u) {
        tab1[u] = sTabH[q * 4 + u];
        tab2[u] = sTabH[16 + q * 4 + u];
    }
    float bias1[8];
#pragma unroll
    for (int nt = 0; nt < 8; ++nt) bias1[nt] = b1c[nt * 16 + c16];

    const f16x8* B1f = (const f16x8*)sB1;
    _Float16* hmw = &sHM[w][0];

#pragma unroll 1
    for (int p2 = 0; p2 < 8; ++p2) {
        const int mA = base + 2 * p2;
        // ---- full-wave staging: lanes 0-31 point A, 32-63 point B ----
        int idx = nbr[(size_t)mA * KK + l];
        float4 pc = pts4[mA + (l >> 5)];
        float4 pn = pts4[bo + idx];
        ushort4 st;
        st.x = h2u((_Float16)(pn.x - pc.x));
        st.y = h2u((_Float16)(pn.y - pc.y));
        st.z = h2u((_Float16)(pn.z - pc.z));
        st.w = (unsigned short)idx;
        sRI[w][l] = st;
        ushort4 eA0 = sRI[w][c16];
        ushort4 eA1 = sRI[w][16 + c16];
        ushort4 eB0 = sRI[w][32 + c16];
        ushort4 eB1 = sRI[w][48 + c16];

        // ---- feature A-frags from fp16 global (MFMA A layout) ----
        f16x8 afA0 = ((const f16x8*)(feat16 + ((size_t)(bo + eA0.w)) * 32))[q];
        f16x8 afA1 = ((const f16x8*)(feat16 + ((size_t)(bo + eA1.w)) * 32))[q];
        f16x8 afB0 = ((const f16x8*)(feat16 + ((size_t)(bo + eB0.w)) * 32))[q];
        f16x8 afB1 = ((const f16x8*)(feat16 + ((size_t)(bo + eB1.w)) * 32))[q];

        // ---- pe A-frags: array-free, packed f16x2 math ----
        f16x8 apA10, apA20, apA11, apA21, apB10, apB20, apB11, apB21;
        PE_FRAGS(eA0, apA10, apA20);
        PE_FRAGS(eA1, apA11, apA21);
        PE_FRAGS(eB0, apB10, apB20);
        PE_FRAGS(eB1, apB11, apB21);

        // ---- per-N-tile: 3 shared B-frags, 12 MFMAs, reduce ----
#pragma unroll 2
        for (int nt = 0; nt < 8; ++nt) {
            f16x8 bf0 = B1f[nt * 64 + l];
            f16x8 bf1 = B1f[(8 + nt) * 64 + l];
            f16x8 bf2 = B1f[(16 + nt) * 64 + l];
            f32x4 aA0, aA1, aB0, aB1;
            aA0[0] = aA0[1] = aA0[2] = aA0[3] = bias1[nt];
            aA1 = aA0; aB0 = aA0; aB1 = aA0;
            aA0 = __builtin_amdgcn_mfma_f32_16x16x32_f16(afA0,  bf0, aA0, 0, 0, 0);
            aA1 = __builtin_amdgcn_mfma_f32_16x16x32_f16(afA1,  bf0, aA1, 0, 0, 0);
            aB0 = __builtin_amdgcn_mfma_f32_16x16x32_f16(afB0,  bf0, aB0, 0, 0, 0);
            aB1 = __builtin_amdgcn_mfma_f32_16x16x32_f16(afB1,  bf0, aB1, 0, 0, 0);
            aA0 = __builtin_amdgcn_mfma_f32_16x16x32_f16(apA10, bf1, aA0, 0, 0, 0);
            aA1 = __builtin_amdgcn_mfma_f32_16x16x32_f16(apA11, bf1, aA1, 0, 0, 0);
            aB0 = __builtin_amdgcn_mfma_f32_16x16x32_f16(apB10, bf1, aB0, 0, 0, 0);
            aB1 = __builtin_amdgcn_mfma_f32_16x16x32_f16(apB11, bf1, aB1, 0, 0, 0);
            aA0 = __builtin_amdgcn_mfma_f32_16x16x32_f16(apA20, bf2, aA0, 0, 0, 0);
            aA1 = __builtin_amdgcn_mfma_f32_16x16x32_f16(apA21, bf2, aA1, 0, 0, 0);
            aB0 = __builtin_amdgcn_mfma_f32_16x16x32_f16(apB20, bf2, aB0, 0, 0, 0);
            aB1 = __builtin_amdgcn_mfma_f32_16x16x32_f16(apB21, bf2, aB1, 0, 0, 0);

            float sA = fmaxf(aA0[0], 0.f) + fmaxf(aA0[1], 0.f)
                     + fmaxf(aA0[2], 0.f) + fmaxf(aA0[3], 0.f)
                     + fmaxf(aA1[0], 0.f) + fmaxf(aA1[1], 0.f)
                     + fmaxf(aA1[2], 0.f) + fmaxf(aA1[3], 0.f);
            float sB = fmaxf(aB0[0], 0.f) + fmaxf(aB0[1], 0.f)
                     + fmaxf(aB0[2], 0.f) + fmaxf(aB0[3], 0.f)
                     + fmaxf(aB1[0], 0.f) + fmaxf(aB1[1], 0.f)
                     + fmaxf(aB1[2], 0.f) + fmaxf(aB1[3], 0.f);
            sA += __shfl_xor(sA, 16, 64);
            sA += __shfl_xor(sA, 32, 64);
            sB += __shfl_xor(sB, 16, 64);
            sB += __shfl_xor(sB, 32, 64);
            if (q == 0) {
                hmw[(2 * p2) * 136 + nt * 16 + c16]     = (_Float16)sA;
                hmw[(2 * p2 + 1) * 136 + nt * 16 + c16] = (_Float16)sB;
            }
        }
    }

    // ---- epilogue: OUT(16x64) = HM(16x128) @ W2s + b2 ----
    const f16x8* W2f = (const f16x8*)gW2;
    f32x4 acc2[4];
#pragma unroll
    for (int nt = 0; nt < 4; ++nt) {
        f32x4 z; float bv = b2g[nt * 16 + c16];
        z[0] = z[1] = z[2] = z[3] = bv;
        acc2[nt] = z;
    }
#pragma unroll
    for (int ks = 0; ks < 4; ++ks) {
        f16x8 a2 = *(const f16x8*)&hmw[c16 * 136 + ks * 32 + q * 8];
#pragma unroll
        for (int nt = 0; nt < 4; ++nt) {
            f16x8 bf = W2f[(ks * 4 + nt) * 64 + l];
            acc2[nt] = __builtin_amdgcn_mfma_f32_16x16x32_f16(a2, bf, acc2[nt], 0, 0, 0);
        }
    }
#pragma unroll
    for (int nt = 0; nt < 4; ++nt)
#pragma unroll
        for (int r = 0; r < 4; ++r)
            out[(size_t)(base + q * 4 + r) * OUTF + nt * 16 + c16] = acc2[nt][r];
}

// ---------------------------------------------------------------------------
extern "C" void kernel_launch(void* const* d_in, const int* in_sizes, int n_in,
                              void* d_out, int out_size, void* d_ws, size_t ws_size,
                              hipStream_t stream)
{
    const float* points   = (const float*)d_in[0];
    const float* features = (const float*)d_in[1];
    // d_in[2] density: provably unused (softmax over K identical values = 1/K)
    const int*   nbr      = (const int*)d_in[3];
    const float* pe_w1    = (const float*)d_in[4];
    const float* pe_b1    = (const float*)d_in[5];
    const float* pe_w2    = (const float*)d_in[6];
    const float* pe_b2    = (const float*)d_in[7];
    const float* mlp_w1   = (const float*)d_in[8];
    const float* mlp_b1   = (const float*)d_in[9];
    const float* mlp_w2   = (const float*)d_in[10];
    const float* mlp_b2   = (const float*)d_in[11];

    float* wsf = (float*)d_ws;
    float*    b1c    = wsf;                         // 128 f32
    _Float16* gB1    = (_Float16*)(wsf + 128);      // 12288 f16
    _Float16* gW2    = (_Float16*)(wsf + 6272);     // 8192 f16
    float4*   pts4   = (float4*)(wsf + 10368);      // 65536 float4
    _Float16* feat16 = (_Float16*)(wsf + 272512);   // 2097152 f16

    prep_all<<<2345, 256, 0, stream>>>(
        pe_w2, pe_b2, mlp_w1, mlp_b1, mlp_w2, features, points,
        gB1, gW2, b1c, feat16, pts4);

    DensityAwareFeatureAggregator_main<<<512, 512, 0, stream>>>(
        pts4, feat16, nbr, pe_w1, pe_b1, b1c, gB1, gW2, mlp_b2,
        (float*)d_out);
}